// Round 1
// baseline (2558.052 us; speedup 1.0000x reference)
//
#include <hip/hip_runtime.h>
#include <math.h>

#define Bc 32
#define Tc 4096
#define Dc 768
#define Hc 1024
#define BTc (Bc*Tc)

__device__ __forceinline__ float gelu_erf(float x) {
  return 0.5f * x * (1.0f + erff(x * 0.70710678118654752440f));
}
// monotone float->uint mapping (order-preserving for all finite floats)
__device__ __forceinline__ unsigned f2o(float f) {
  unsigned b = __float_as_uint(f);
  return (b & 0x80000000u) ? ~b : (b | 0x80000000u);
}
__device__ __forceinline__ float o2f(unsigned o) {
  unsigned b = (o & 0x80000000u) ? (o & 0x7FFFFFFFu) : ~o;
  return __uint_as_float(b);
}

// ---------------- Kernel 1: masked LayerNorm stats (mu, rstd per row) -------
__global__ __launch_bounds__(256) void ln_stats_k(
    const float* __restrict__ emb, const float* __restrict__ attn,
    float* __restrict__ mu, float* __restrict__ rstd) {
  int row = blockIdx.x * 4 + (threadIdx.x >> 6);
  int lane = threadIdx.x & 63;
  float a = attn[row];
  const float4* e = (const float4*)(emb + (size_t)row * Dc);
  float4 v0 = e[lane], v1 = e[lane + 64], v2 = e[lane + 128];
  float x[12] = {v0.x*a, v0.y*a, v0.z*a, v0.w*a,
                 v1.x*a, v1.y*a, v1.z*a, v1.w*a,
                 v2.x*a, v2.y*a, v2.z*a, v2.w*a};
  float s = 0.f;
  #pragma unroll
  for (int i = 0; i < 12; i++) s += x[i];
  #pragma unroll
  for (int o = 32; o; o >>= 1) s += __shfl_xor(s, o);
  float m = s / 768.0f;
  float q = 0.f;
  #pragma unroll
  for (int i = 0; i < 12; i++) { float d = x[i] - m; q += d * d; }
  #pragma unroll
  for (int o = 32; o; o >>= 1) q += __shfl_xor(q, o);
  float var = q / 768.0f;
  if (lane == 0) { mu[row] = m; rstd[row] = 1.0f / sqrtf(var + 1e-5f); }
}

// ------- Kernel 2: fused (LN-apply -> xn@W1+b1 -> erf-gelu -> @W2+b2) -------
// 128x128 tile per block over the H loop, 256 threads, 8x8 micro-tile.
__global__ __launch_bounds__(256) void gemm_scores_k(
    const float* __restrict__ emb, const float* __restrict__ attn,
    const float* __restrict__ ln_g, const float* __restrict__ ln_b,
    const float* __restrict__ W1, const float* __restrict__ b1,
    const float* __restrict__ W2, const float* __restrict__ b2,
    const float* __restrict__ mu, const float* __restrict__ rstd,
    float* __restrict__ scores) {
  __shared__ float As[16][128];   // A tile transposed: As[k][m]
  __shared__ float Bs[16][128];   // B tile: Bs[k][n]
  __shared__ float bws[2048];     // b1[0..1023], W2[1024..2047]
  __shared__ float red[16][128];  // cross-thread score reduction
  const int b = blockIdx.y;
  const int tile0 = blockIdx.x * 128;
  const int t = threadIdx.x;
  if (attn[b * Tc + tile0] == 0.0f) return;  // attn is a prefix mask
  for (int i = t; i < 1024; i += 256) { bws[i] = b1[i]; bws[1024 + i] = W2[i]; }
  // A staging indices: thread loads 8 consecutive k for one row
  const int lm = t >> 1;
  const int lk = (t & 1) * 8;
  const int grow = b * Tc + tile0 + lm;
  const float la = attn[grow];
  const float lmu = mu[grow];
  const float lrs = rstd[grow];
  const float* aptr = emb + (size_t)grow * Dc;
  // B staging indices
  const int bk = t >> 4;
  const int bn = (t & 15) * 8;
  const float* wbase = W1 + (size_t)bk * Hc + bn;
  // micro-tile: rows {rm..rm+3, rm+64..rm+67}, cols {cn..cn+3, cn+64..cn+67}
  const int rm = (t & 15) * 4;
  const int cn = (t >> 4) * 4;
  float sacc[8] = {0, 0, 0, 0, 0, 0, 0, 0};
  for (int n0 = 0; n0 < Hc; n0 += 128) {
    float acc[8][8];
    #pragma unroll
    for (int i = 0; i < 8; i++)
      #pragma unroll
      for (int j = 0; j < 8; j++) acc[i][j] = 0.0f;
    for (int k0 = 0; k0 < Dc; k0 += 16) {
      __syncthreads();
      const float4* ap4 = (const float4*)(aptr + k0 + lk);
      float4 e0 = ap4[0], e1 = ap4[1];
      const float4* gp4 = (const float4*)(ln_g + k0 + lk);
      float4 g0 = gp4[0], g1 = gp4[1];
      const float4* lp4 = (const float4*)(ln_b + k0 + lk);
      float4 l0 = lp4[0], l1 = lp4[1];
      float ev[8] = {e0.x, e0.y, e0.z, e0.w, e1.x, e1.y, e1.z, e1.w};
      float gv[8] = {g0.x, g0.y, g0.z, g0.w, g1.x, g1.y, g1.z, g1.w};
      float lv[8] = {l0.x, l0.y, l0.z, l0.w, l1.x, l1.y, l1.z, l1.w};
      #pragma unroll
      for (int ii = 0; ii < 8; ii++)
        As[lk + ii][lm] = (ev[ii] * la - lmu) * lrs * gv[ii] + lv[ii];
      const float* wp = wbase + (size_t)k0 * Hc + n0;
      float4 w0 = ((const float4*)wp)[0];
      float4 w1 = ((const float4*)wp)[1];
      *(float4*)&Bs[bk][bn] = w0;
      *(float4*)&Bs[bk][bn + 4] = w1;
      __syncthreads();
      #pragma unroll
      for (int kk = 0; kk < 16; kk++) {
        float av[8], bv[8];
        *(float4*)&av[0] = *(const float4*)&As[kk][rm];
        *(float4*)&av[4] = *(const float4*)&As[kk][rm + 64];
        *(float4*)&bv[0] = *(const float4*)&Bs[kk][cn];
        *(float4*)&bv[4] = *(const float4*)&Bs[kk][cn + 64];
        #pragma unroll
        for (int i = 0; i < 8; i++)
          #pragma unroll
          for (int j = 0; j < 8; j++)
            acc[i][j] = fmaf(av[i], bv[j], acc[i][j]);
      }
    }
    // epilogue: gelu + dot with W2 chunk
    #pragma unroll
    for (int j = 0; j < 8; j++) {
      int cl = (j < 4) ? (cn + j) : (cn + 60 + j);
      int col = n0 + cl;
      float bb = bws[col], w2v = bws[1024 + col];
      #pragma unroll
      for (int i = 0; i < 8; i++)
        sacc[i] += gelu_erf(acc[i][j] + bb) * w2v;
    }
  }
  __syncthreads();
  #pragma unroll
  for (int i = 0; i < 8; i++) {
    int rowl = (i < 4) ? (rm + i) : (rm + 60 + i);
    red[t >> 4][rowl] = sacc[i];
  }
  __syncthreads();
  if (t < 128) {
    float sv = 0.f;
    #pragma unroll
    for (int g2 = 0; g2 < 16; g2++) sv += red[g2][t];
    scores[b * Tc + tile0 + t] = sv + b2[0];
  }
}

// ---- Kernel 3: 1.5-entmax (f64 tau), exact stable ranking, h-mask writes ---
__global__ __launch_bounds__(256) void entmax_rank_k(
    const float* __restrict__ scores, const float* __restrict__ attn,
    float* __restrict__ out) {
  const int N = 4096;
  __shared__ unsigned long long keys[4096];  // (orderable(score)<<32)|(~idx)
  __shared__ double tsum[256], tsq[256];
  __shared__ int tcnt[256];
  __shared__ float sred[4];
  __shared__ double sh_tau;
  __shared__ int sh_S, sh_m, sh_k[5];
  const int b = blockIdx.x;
  const int t = threadIdx.x;
  const float* srow = scores + b * N;
  const float* arow = attn + b * N;
  // build sort keys; reduce t_eff
  float teff_l = 0.f;
  for (int i = t; i < N; i += 256) {
    float a = arow[i];
    float s = srow[i];
    float xe = (a == 0.f) ? -1e9f : s;  // ref: where(attn==0, -1e9, scores)
    teff_l += a;
    keys[i] = ((unsigned long long)f2o(xe) << 32) |
              (unsigned long long)(0xFFFFFFFFu - (unsigned)i);
  }
  #pragma unroll
  for (int o = 32; o; o >>= 1) teff_l += __shfl_xor(teff_l, o);
  if ((t & 63) == 0) sred[t >> 6] = teff_l;
  __syncthreads();
  if (t == 0) {
    float te = sred[0] + sred[1] + sred[2] + sred[3];
    // k = max(1, floor(rho_f32 * t_eff_f32))  -- must be f32 math!
    const float rh[5] = {0.1f, 0.3f, 0.5f, 0.7f, 0.9f};
    for (int r = 0; r < 5; r++) {
      int ki = (int)floorf(rh[r] * te);
      sh_k[r] = ki < 1 ? 1 : ki;
    }
  }
  // bitonic sort, descending by key (score desc, idx asc on ties)
  for (int kk = 2; kk <= N; kk <<= 1) {
    for (int j = kk >> 1; j > 0; j >>= 1) {
      __syncthreads();
      for (int idx = t; idx < N / 2; idx += 256) {
        int i = 2 * idx - (idx & (j - 1));
        int l = i | j;
        unsigned long long A = keys[i], Bv = keys[l];
        bool up = ((i & kk) == 0);
        if (up ? (A < Bv) : (A > Bv)) { keys[i] = Bv; keys[l] = A; }
      }
    }
  }
  __syncthreads();
  // f64 prefix scan of (x, x^2) over sorted x = score/2  (TAU=1, entmax /2)
  const int base = t * 16;
  {
    double ls = 0, lq = 0;
    for (int ii = 0; ii < 16; ii++) {
      double x = 0.5 * (double)o2f((unsigned)(keys[base + ii] >> 32));
      ls += x; lq += x * x;
    }
    tsum[t] = ls; tsq[t] = lq;
  }
  __syncthreads();
  if (t == 0) {
    double rs = 0, rq = 0;
    for (int i = 0; i < 256; i++) {
      double a = tsum[i], c = tsq[i];
      tsum[i] = rs; tsq[i] = rq; rs += a; rq += c;
    }
  }
  __syncthreads();
  // support count S = sum_j [tau_j <= x_srt_j]
  {
    double cs = tsum[t], cq = tsq[t];
    int lc = 0;
    for (int ii = 0; ii < 16; ii++) {
      double x = 0.5 * (double)o2f((unsigned)(keys[base + ii] >> 32));
      cs += x; cq += x * x;
      double rho = (double)(base + ii + 1);
      double mean = cs / rho, msq = cq / rho;
      double ss = rho * (msq - mean * mean);
      double delta = (1.0 - ss) / rho;
      double dl = delta > 0.0 ? delta : 0.0;
      double tau = mean - sqrt(dl);
      if (tau <= x) lc++;
    }
    tcnt[t] = lc;
  }
  __syncthreads();
  if (t == 0) {
    int r = 0;
    for (int i = 0; i < 256; i++) { int c = tcnt[i]; tcnt[i] = r; r += c; }
    sh_S = r;
  }
  __syncthreads();
  // tau_star = tau[S-1], recomputed by the owning thread
  {
    int jstar = sh_S - 1;
    if (jstar >= base && jstar < base + 16) {
      double cs = tsum[t], cq = tsq[t], tau = 0.0;
      for (int ii = 0; ii <= jstar - base; ii++) {
        double x = 0.5 * (double)o2f((unsigned)(keys[base + ii] >> 32));
        cs += x; cq += x * x;
        double rho = (double)(base + ii + 1);
        double mean = cs / rho, msq = cq / rho;
        double ss = rho * (msq - mean * mean);
        double delta = (1.0 - ss) / rho;
        double dl = delta > 0.0 ? delta : 0.0;
        tau = mean - sqrt(dl);
      }
      sh_tau = tau;
    }
  }
  __syncthreads();
  const double tau = sh_tau;
  // original-order pass: support flags exclusive scan
  float ps[16], pa[16];
  {
    int lf = 0;
    for (int ii = 0; ii < 16; ii++) {
      int p = base + ii;
      ps[ii] = srow[p]; pa[ii] = arow[p];
      double d = 0.5 * (double)ps[ii] - tau;
      if (pa[ii] != 0.f && d > 0.0) lf++;
    }
    tcnt[t] = lf;
  }
  __syncthreads();
  if (t == 0) {
    int r = 0;
    for (int i = 0; i < 256; i++) { int c = tcnt[i]; tcnt[i] = r; r += c; }
    sh_m = r;
  }
  __syncthreads();
  const int m = sh_m;
  const int k0_ = sh_k[0], k1_ = sh_k[1], k2_ = sh_k[2], k3_ = sh_k[3], k4_ = sh_k[4];
  // write z everywhere; write h for zero-z positions (rank = m + #zeros before)
  {
    int cex = tcnt[t];
    for (int ii = 0; ii < 16; ii++) {
      int p = base + ii;
      double d = 0.5 * (double)ps[ii] - tau;
      bool av = (pa[ii] != 0.f);
      bool sup = av && (d > 0.0);
      out[b * N + p] = sup ? (float)(d * d) : 0.0f;
      if (!sup) {
        int rank = m + p - cex;
        out[1 * BTc + b * N + p] = (av && rank < k0_) ? 1.f : 0.f;
        out[2 * BTc + b * N + p] = (av && rank < k1_) ? 1.f : 0.f;
        out[3 * BTc + b * N + p] = (av && rank < k2_) ? 1.f : 0.f;
        out[4 * BTc + b * N + p] = (av && rank < k3_) ? 1.f : 0.f;
        out[5 * BTc + b * N + p] = (av && rank < k4_) ? 1.f : 0.f;
      } else {
        cex++;
      }
    }
  }
  // support positions: rank = sorted slot (z desc == score desc above tau)
  for (int r = t; r < m; r += 256) {
    int i = (int)(0xFFFFFFFFu - (unsigned)(keys[r] & 0xFFFFFFFFull));
    out[1 * BTc + b * N + i] = (r < k0_) ? 1.f : 0.f;
    out[2 * BTc + b * N + i] = (r < k1_) ? 1.f : 0.f;
    out[3 * BTc + b * N + i] = (r < k2_) ? 1.f : 0.f;
    out[4 * BTc + b * N + i] = (r < k3_) ? 1.f : 0.f;
    out[5 * BTc + b * N + i] = (r < k4_) ? 1.f : 0.f;
  }
}

extern "C" void kernel_launch(void* const* d_in, const int* in_sizes, int n_in,
                              void* d_out, int out_size, void* d_ws, size_t ws_size,
                              hipStream_t stream) {
  (void)in_sizes; (void)n_in; (void)out_size; (void)ws_size;
  const float* emb  = (const float*)d_in[0];
  const float* attn = (const float*)d_in[1];
  const float* ln_g = (const float*)d_in[2];
  const float* ln_b = (const float*)d_in[3];
  const float* W1   = (const float*)d_in[4];
  const float* b1   = (const float*)d_in[5];
  const float* W2   = (const float*)d_in[6];
  const float* b2   = (const float*)d_in[7];
  float* out = (float*)d_out;
  float* wsf = (float*)d_ws;
  float* mu     = wsf;
  float* rstd   = wsf + BTc;
  float* scores = wsf + 2 * BTc;

  ln_stats_k<<<BTc / 4, 256, 0, stream>>>(emb, attn, mu, rstd);
  gemm_scores_k<<<dim3(Tc / 128, Bc), 256, 0, stream>>>(
      emb, attn, ln_g, ln_b, W1, b1, W2, b2, mu, rstd, scores);
  entmax_rank_k<<<Bc, 256, 0, stream>>>(scores, attn, out);
}

// Round 2
// 1601.230 us; speedup vs baseline: 1.5976x; 1.5976x over previous
//
#include <hip/hip_runtime.h>
#include <math.h>

#define Bc 32
#define Tc 4096
#define Dc 768
#define Hc 1024
#define BTc (Bc*Tc)

typedef __bf16 bf16x8 __attribute__((ext_vector_type(8)));
typedef float f32x16 __attribute__((ext_vector_type(16)));

__device__ __forceinline__ float gelu_erf(float x) {
  return 0.5f * x * (1.0f + erff(x * 0.70710678118654752440f));
}
// round-to-nearest-even f32 -> bf16 (finite inputs)
__device__ __forceinline__ unsigned bf16rne(float x) {
  unsigned u = __float_as_uint(x);
  return (u + 0x7FFFu + ((u >> 16) & 1u)) >> 16;
}
// exact 3-way bf16 split: x ~= hi+mid+lo, residual ~2^-27 |x|
__device__ __forceinline__ void split3(float x, unsigned& h, unsigned& m, unsigned& l) {
  h = bf16rne(x);
  float r1 = x - __uint_as_float(h << 16);
  m = bf16rne(r1);
  float r2 = r1 - __uint_as_float(m << 16);
  l = bf16rne(r2);
}
// monotone float->uint mapping (order-preserving)
__device__ __forceinline__ unsigned f2o(float f) {
  unsigned b = __float_as_uint(f);
  return (b & 0x80000000u) ? ~b : (b | 0x80000000u);
}
__device__ __forceinline__ float o2f(unsigned o) {
  unsigned b = (o & 0x80000000u) ? (o & 0x7FFFFFFFu) : ~o;
  return __uint_as_float(b);
}

// ---------------- Kernel 1: masked LayerNorm stats (mu, rstd per row) -------
__global__ __launch_bounds__(256) void ln_stats_k(
    const float* __restrict__ emb, const float* __restrict__ attn,
    float* __restrict__ mu, float* __restrict__ rstd) {
  int row = blockIdx.x * 4 + (threadIdx.x >> 6);
  int lane = threadIdx.x & 63;
  float a = attn[row];
  const float4* e = (const float4*)(emb + (size_t)row * Dc);
  float4 v0 = e[lane], v1 = e[lane + 64], v2 = e[lane + 128];
  float x[12] = {v0.x*a, v0.y*a, v0.z*a, v0.w*a,
                 v1.x*a, v1.y*a, v1.z*a, v1.w*a,
                 v2.x*a, v2.y*a, v2.z*a, v2.w*a};
  float s = 0.f;
  #pragma unroll
  for (int i = 0; i < 12; i++) s += x[i];
  #pragma unroll
  for (int o = 32; o; o >>= 1) s += __shfl_xor(s, o);
  float m = s / 768.0f;
  float q = 0.f;
  #pragma unroll
  for (int i = 0; i < 12; i++) { float d = x[i] - m; q += d * d; }
  #pragma unroll
  for (int o = 32; o; o >>= 1) q += __shfl_xor(q, o);
  float var = q / 768.0f;
  if (lane == 0) { mu[row] = m; rstd[row] = 1.0f / sqrtf(var + 1e-5f); }
}

// ------- Kernel 2: MFMA bf16x3 (6-pass) fused LN->GEMM1->gelu->GEMM2 -------
// 128 rows per block, 4 waves x (32 rows x 128 cols), N loop of 8 x 128-tiles,
// K loop BK=32. LDS: [split][kgroup][row] 16B chunks -> linear frag reads.
__global__ __launch_bounds__(256, 2) void gemm_scores_mfma(
    const float* __restrict__ emb, const float* __restrict__ attn,
    const float* __restrict__ ln_g, const float* __restrict__ ln_b,
    const float* __restrict__ W1, const float* __restrict__ b1,
    const float* __restrict__ W2, const float* __restrict__ b2,
    const float* __restrict__ mu, const float* __restrict__ rstd,
    float* __restrict__ scores) {
  __shared__ int4 AlB[3][4][128];   // 24 KB: A splits h/m/l
  __shared__ int4 BlB[3][4][128];   // 24 KB: B splits h/m/l
  const int base = blockIdx.x * 128;
  if (attn[base] == 0.0f) return;   // attn is a prefix mask; strip fully dead
  const int t = threadIdx.x;
  const int lane = t & 63;
  const int lrow = lane & 31;       // M-row (A) / N-col (B) within 32-tile
  const int lkg = lane >> 5;        // k-subgroup select
  const int w = t >> 6;             // wave id: owns rows [w*32, w*32+32)

  // staging role: one A-row and one B-col per thread, 2 k-chunks each
  const int srow = t & 127;
  const int kgA = t >> 7;           // 0/1 (+2 for second chunk)
  const float la  = attn[base + srow];
  const float lmu = mu[base + srow];
  const float lrs = rstd[base + srow];
  const float* erow = emb + (size_t)(base + srow) * Dc;

  float sacc[16];
  #pragma unroll
  for (int r = 0; r < 16; r++) sacc[r] = 0.f;

  for (int n0 = 0; n0 < Hc; n0 += 128) {
    f32x16 acc[4];
    #pragma unroll
    for (int nt = 0; nt < 4; nt++)
      #pragma unroll
      for (int r = 0; r < 16; r++) acc[nt][r] = 0.f;

    for (int k0 = 0; k0 < Dc; k0 += 32) {
      __syncthreads();
      // ---- stage A (LN-apply + split3), 2 chunks of 8 k each ----
      #pragma unroll
      for (int ci = 0; ci < 2; ci++) {
        const int kg = kgA + 2 * ci;
        const int kb = k0 + kg * 8;
        const float4* ep = (const float4*)(erow + kb);
        float4 e0 = ep[0], e1 = ep[1];
        const float4* gp = (const float4*)(ln_g + kb);
        float4 g0 = gp[0], g1 = gp[1];
        const float4* bp = (const float4*)(ln_b + kb);
        float4 q0 = bp[0], q1 = bp[1];
        float xv[8] = {e0.x,e0.y,e0.z,e0.w,e1.x,e1.y,e1.z,e1.w};
        float gv[8] = {g0.x,g0.y,g0.z,g0.w,g1.x,g1.y,g1.z,g1.w};
        float bv[8] = {q0.x,q0.y,q0.z,q0.w,q1.x,q1.y,q1.z,q1.w};
        unsigned hs[8], ms[8], ls[8];
        #pragma unroll
        for (int e = 0; e < 8; e++) {
          float xn = (xv[e] * la - lmu) * lrs * gv[e] + bv[e];
          split3(xn, hs[e], ms[e], ls[e]);
        }
        int4 ph, pm, pl;
        ph.x = (int)(hs[0] | (hs[1] << 16)); ph.y = (int)(hs[2] | (hs[3] << 16));
        ph.z = (int)(hs[4] | (hs[5] << 16)); ph.w = (int)(hs[6] | (hs[7] << 16));
        pm.x = (int)(ms[0] | (ms[1] << 16)); pm.y = (int)(ms[2] | (ms[3] << 16));
        pm.z = (int)(ms[4] | (ms[5] << 16)); pm.w = (int)(ms[6] | (ms[7] << 16));
        pl.x = (int)(ls[0] | (ls[1] << 16)); pl.y = (int)(ls[2] | (ls[3] << 16));
        pl.z = (int)(ls[4] | (ls[5] << 16)); pl.w = (int)(ls[6] | (ls[7] << 16));
        AlB[0][kg][srow] = ph; AlB[1][kg][srow] = pm; AlB[2][kg][srow] = pl;
      }
      // ---- stage B (W1 split3), 2 chunks ----
      #pragma unroll
      for (int ci = 0; ci < 2; ci++) {
        const int kg = kgA + 2 * ci;
        const int kb = k0 + kg * 8;
        const float* wp = W1 + (size_t)kb * Hc + n0 + srow;
        unsigned hs[8], ms[8], ls[8];
        #pragma unroll
        for (int j = 0; j < 8; j++) {
          float x = wp[(size_t)j * Hc];
          split3(x, hs[j], ms[j], ls[j]);
        }
        int4 ph, pm, pl;
        ph.x = (int)(hs[0] | (hs[1] << 16)); ph.y = (int)(hs[2] | (hs[3] << 16));
        ph.z = (int)(hs[4] | (hs[5] << 16)); ph.w = (int)(hs[6] | (hs[7] << 16));
        pm.x = (int)(ms[0] | (ms[1] << 16)); pm.y = (int)(ms[2] | (ms[3] << 16));
        pm.z = (int)(ms[4] | (ms[5] << 16)); pm.w = (int)(ms[6] | (ms[7] << 16));
        pl.x = (int)(ls[0] | (ls[1] << 16)); pl.y = (int)(ls[2] | (ls[3] << 16));
        pl.z = (int)(ls[4] | (ls[5] << 16)); pl.w = (int)(ls[6] | (ls[7] << 16));
        BlB[0][kg][srow] = ph; BlB[1][kg][srow] = pm; BlB[2][kg][srow] = pl;
      }
      __syncthreads();
      // ---- MFMA: 6-pass bf16x3 emulated-f32, 2 x K=16 halves ----
      #pragma unroll
      for (int kh = 0; kh < 2; kh++) {
        const int kg = kh * 2 + lkg;
        bf16x8 af[3];
        #pragma unroll
        for (int s = 0; s < 3; s++)
          af[s] = *(const bf16x8*)&AlB[s][kg][w * 32 + lrow];
        bf16x8 bfr[4][3];
        #pragma unroll
        for (int nt = 0; nt < 4; nt++)
          #pragma unroll
          for (int s = 0; s < 3; s++)
            bfr[nt][s] = *(const bf16x8*)&BlB[s][kg][nt * 32 + lrow];
        #pragma unroll
        for (int nt = 0; nt < 4; nt++) {
          acc[nt] = __builtin_amdgcn_mfma_f32_32x32x16_bf16(af[0], bfr[nt][0], acc[nt], 0, 0, 0);
          acc[nt] = __builtin_amdgcn_mfma_f32_32x32x16_bf16(af[0], bfr[nt][1], acc[nt], 0, 0, 0);
          acc[nt] = __builtin_amdgcn_mfma_f32_32x32x16_bf16(af[1], bfr[nt][0], acc[nt], 0, 0, 0);
          acc[nt] = __builtin_amdgcn_mfma_f32_32x32x16_bf16(af[1], bfr[nt][1], acc[nt], 0, 0, 0);
          acc[nt] = __builtin_amdgcn_mfma_f32_32x32x16_bf16(af[0], bfr[nt][2], acc[nt], 0, 0, 0);
          acc[nt] = __builtin_amdgcn_mfma_f32_32x32x16_bf16(af[2], bfr[nt][0], acc[nt], 0, 0, 0);
        }
      }
    }
    // ---- epilogue: bias + erf-gelu + dot with W2 chunk ----
    #pragma unroll
    for (int nt = 0; nt < 4; nt++) {
      const int col = n0 + nt * 32 + lrow;
      const float b1v = b1[col];
      const float w2v = W2[col];
      #pragma unroll
      for (int r = 0; r < 16; r++)
        sacc[r] += gelu_erf(acc[nt][r] + b1v) * w2v;
    }
  }
  // ---- reduce across 32 col-lanes, write scores ----
  const float b2v = b2[0];
  #pragma unroll
  for (int r = 0; r < 16; r++) {
    float v = sacc[r];
    v += __shfl_xor(v, 1);  v += __shfl_xor(v, 2);  v += __shfl_xor(v, 4);
    v += __shfl_xor(v, 8);  v += __shfl_xor(v, 16);
    if (lrow == 0) {
      int row = w * 32 + (r & 3) + 8 * (r >> 2) + 4 * lkg;
      scores[base + row] = v + b2v;
    }
  }
}

// ---- Kernel 3: 1.5-entmax (f64 tau), exact stable ranking, h-mask writes ---
__global__ __launch_bounds__(256) void entmax_rank_k(
    const float* __restrict__ scores, const float* __restrict__ attn,
    float* __restrict__ out) {
  const int N = 4096;
  __shared__ unsigned long long keys[4096];  // (orderable(score)<<32)|(~idx)
  __shared__ double tsum[256], tsq[256];
  __shared__ int tcnt[256];
  __shared__ float sred[4];
  __shared__ double sh_tau;
  __shared__ int sh_S, sh_m, sh_k[5];
  const int b = blockIdx.x;
  const int t = threadIdx.x;
  const float* srow = scores + b * N;
  const float* arow = attn + b * N;
  float teff_l = 0.f;
  for (int i = t; i < N; i += 256) {
    float a = arow[i];
    float s = srow[i];
    float xe = (a == 0.f) ? -1e9f : s;
    teff_l += a;
    keys[i] = ((unsigned long long)f2o(xe) << 32) |
              (unsigned long long)(0xFFFFFFFFu - (unsigned)i);
  }
  #pragma unroll
  for (int o = 32; o; o >>= 1) teff_l += __shfl_xor(teff_l, o);
  if ((t & 63) == 0) sred[t >> 6] = teff_l;
  __syncthreads();
  if (t == 0) {
    float te = sred[0] + sred[1] + sred[2] + sred[3];
    const float rh[5] = {0.1f, 0.3f, 0.5f, 0.7f, 0.9f};
    for (int r = 0; r < 5; r++) {
      int ki = (int)floorf(rh[r] * te);   // must be f32 math
      sh_k[r] = ki < 1 ? 1 : ki;
    }
  }
  for (int kk = 2; kk <= N; kk <<= 1) {
    for (int j = kk >> 1; j > 0; j >>= 1) {
      __syncthreads();
      for (int idx = t; idx < N / 2; idx += 256) {
        int i = 2 * idx - (idx & (j - 1));
        int l = i | j;
        unsigned long long A = keys[i], Bv = keys[l];
        bool up = ((i & kk) == 0);
        if (up ? (A < Bv) : (A > Bv)) { keys[i] = Bv; keys[l] = A; }
      }
    }
  }
  __syncthreads();
  const int base = t * 16;
  {
    double ls = 0, lq = 0;
    for (int ii = 0; ii < 16; ii++) {
      double x = 0.5 * (double)o2f((unsigned)(keys[base + ii] >> 32));
      ls += x; lq += x * x;
    }
    tsum[t] = ls; tsq[t] = lq;
  }
  __syncthreads();
  if (t == 0) {
    double rs = 0, rq = 0;
    for (int i = 0; i < 256; i++) {
      double a = tsum[i], c = tsq[i];
      tsum[i] = rs; tsq[i] = rq; rs += a; rq += c;
    }
  }
  __syncthreads();
  {
    double cs = tsum[t], cq = tsq[t];
    int lc = 0;
    for (int ii = 0; ii < 16; ii++) {
      double x = 0.5 * (double)o2f((unsigned)(keys[base + ii] >> 32));
      cs += x; cq += x * x;
      double rho = (double)(base + ii + 1);
      double mean = cs / rho, msq = cq / rho;
      double ss = rho * (msq - mean * mean);
      double delta = (1.0 - ss) / rho;
      double dl = delta > 0.0 ? delta : 0.0;
      double tau = mean - sqrt(dl);
      if (tau <= x) lc++;
    }
    tcnt[t] = lc;
  }
  __syncthreads();
  if (t == 0) {
    int r = 0;
    for (int i = 0; i < 256; i++) { int c = tcnt[i]; tcnt[i] = r; r += c; }
    sh_S = r;
  }
  __syncthreads();
  {
    int jstar = sh_S - 1;
    if (jstar >= base && jstar < base + 16) {
      double cs = tsum[t], cq = tsq[t], tau = 0.0;
      for (int ii = 0; ii <= jstar - base; ii++) {
        double x = 0.5 * (double)o2f((unsigned)(keys[base + ii] >> 32));
        cs += x; cq += x * x;
        double rho = (double)(base + ii + 1);
        double mean = cs / rho, msq = cq / rho;
        double ss = rho * (msq - mean * mean);
        double delta = (1.0 - ss) / rho;
        double dl = delta > 0.0 ? delta : 0.0;
        tau = mean - sqrt(dl);
      }
      sh_tau = tau;
    }
  }
  __syncthreads();
  const double tau = sh_tau;
  float ps[16], pa[16];
  {
    int lf = 0;
    for (int ii = 0; ii < 16; ii++) {
      int p = base + ii;
      ps[ii] = srow[p]; pa[ii] = arow[p];
      double d = 0.5 * (double)ps[ii] - tau;
      if (pa[ii] != 0.f && d > 0.0) lf++;
    }
    tcnt[t] = lf;
  }
  __syncthreads();
  if (t == 0) {
    int r = 0;
    for (int i = 0; i < 256; i++) { int c = tcnt[i]; tcnt[i] = r; r += c; }
    sh_m = r;
  }
  __syncthreads();
  const int m = sh_m;
  const int k0_ = sh_k[0], k1_ = sh_k[1], k2_ = sh_k[2], k3_ = sh_k[3], k4_ = sh_k[4];
  {
    int cex = tcnt[t];
    for (int ii = 0; ii < 16; ii++) {
      int p = base + ii;
      double d = 0.5 * (double)ps[ii] - tau;
      bool av = (pa[ii] != 0.f);
      bool sup = av && (d > 0.0);
      out[b * N + p] = sup ? (float)(d * d) : 0.0f;
      if (!sup) {
        int rank = m + p - cex;
        out[1 * BTc + b * N + p] = (av && rank < k0_) ? 1.f : 0.f;
        out[2 * BTc + b * N + p] = (av && rank < k1_) ? 1.f : 0.f;
        out[3 * BTc + b * N + p] = (av && rank < k2_) ? 1.f : 0.f;
        out[4 * BTc + b * N + p] = (av && rank < k3_) ? 1.f : 0.f;
        out[5 * BTc + b * N + p] = (av && rank < k4_) ? 1.f : 0.f;
      } else {
        cex++;
      }
    }
  }
  for (int r = t; r < m; r += 256) {
    int i = (int)(0xFFFFFFFFu - (unsigned)(keys[r] & 0xFFFFFFFFull));
    out[1 * BTc + b * N + i] = (r < k0_) ? 1.f : 0.f;
    out[2 * BTc + b * N + i] = (r < k1_) ? 1.f : 0.f;
    out[3 * BTc + b * N + i] = (r < k2_) ? 1.f : 0.f;
    out[4 * BTc + b * N + i] = (r < k3_) ? 1.f : 0.f;
    out[5 * BTc + b * N + i] = (r < k4_) ? 1.f : 0.f;
  }
}

extern "C" void kernel_launch(void* const* d_in, const int* in_sizes, int n_in,
                              void* d_out, int out_size, void* d_ws, size_t ws_size,
                              hipStream_t stream) {
  (void)in_sizes; (void)n_in; (void)out_size; (void)ws_size;
  const float* emb  = (const float*)d_in[0];
  const float* attn = (const float*)d_in[1];
  const float* ln_g = (const float*)d_in[2];
  const float* ln_b = (const float*)d_in[3];
  const float* W1   = (const float*)d_in[4];
  const float* b1   = (const float*)d_in[5];
  const float* W2   = (const float*)d_in[6];
  const float* b2   = (const float*)d_in[7];
  float* out = (float*)d_out;
  float* wsf = (float*)d_ws;
  float* mu     = wsf;
  float* rstd   = wsf + BTc;
  float* scores = wsf + 2 * BTc;

  ln_stats_k<<<BTc / 4, 256, 0, stream>>>(emb, attn, mu, rstd);
  gemm_scores_mfma<<<BTc / 128, 256, 0, stream>>>(
      emb, attn, ln_g, ln_b, W1, b1, W2, b2, mu, rstd, scores);
  entmax_rank_k<<<Bc, 256, 0, stream>>>(scores, attn, out);
}

// Round 3
// 1586.162 us; speedup vs baseline: 1.6127x; 1.0095x over previous
//
#include <hip/hip_runtime.h>
#include <math.h>

#define Bc 32
#define Tc 4096
#define Dc 768
#define Hc 1024
#define BTc (Bc*Tc)
#define PLANE 786432   // 96*1024*8 ushorts per split plane

typedef __bf16 bf16x8 __attribute__((ext_vector_type(8)));
typedef float f32x16 __attribute__((ext_vector_type(16)));

__device__ __forceinline__ float gelu_erf(float x) {
  return 0.5f * x * (1.0f + erff(x * 0.70710678118654752440f));
}
__device__ __forceinline__ unsigned bf16rne(float x) {
  unsigned u = __float_as_uint(x);
  return (u + 0x7FFFu + ((u >> 16) & 1u)) >> 16;
}
// exact 3-way bf16 split: x ~= hi+mid+lo, residual ~2^-27 |x|
__device__ __forceinline__ void split3(float x, unsigned& h, unsigned& m, unsigned& l) {
  h = bf16rne(x);
  float r1 = x - __uint_as_float(h << 16);
  m = bf16rne(r1);
  float r2 = r1 - __uint_as_float(m << 16);
  l = bf16rne(r2);
}
__device__ __forceinline__ unsigned f2o(float f) {
  unsigned b = __float_as_uint(f);
  return (b & 0x80000000u) ? ~b : (b | 0x80000000u);
}
__device__ __forceinline__ float o2f(unsigned o) {
  unsigned b = (o & 0x80000000u) ? (o & 0x7FFFFFFFu) : ~o;
  return __uint_as_float(b);
}

// ---------------- Kernel 0: pre-split W1 into 3 bf16 planes -----------------
// layout: w1s[s*PLANE + (kg*1024 + n)*8 + j]  for element (k=kg*8+j, n)
__global__ __launch_bounds__(256) void w1_split_k(
    const float* __restrict__ W1, ushort* __restrict__ w1s) {
  int id = blockIdx.x * 256 + threadIdx.x;   // 96*1024 total
  int n = id & 1023, kg = id >> 10;
  unsigned hs[8], ms[8], ls[8];
  #pragma unroll
  for (int j = 0; j < 8; j++) {
    float x = W1[(size_t)(kg * 8 + j) * Hc + n];
    split3(x, hs[j], ms[j], ls[j]);
  }
  size_t o = ((size_t)kg * 1024 + n) * 8;
  int4 ph, pm, pl;
  ph.x = (int)(hs[0] | (hs[1] << 16)); ph.y = (int)(hs[2] | (hs[3] << 16));
  ph.z = (int)(hs[4] | (hs[5] << 16)); ph.w = (int)(hs[6] | (hs[7] << 16));
  pm.x = (int)(ms[0] | (ms[1] << 16)); pm.y = (int)(ms[2] | (ms[3] << 16));
  pm.z = (int)(ms[4] | (ms[5] << 16)); pm.w = (int)(ms[6] | (ms[7] << 16));
  pl.x = (int)(ls[0] | (ls[1] << 16)); pl.y = (int)(ls[2] | (ls[3] << 16));
  pl.z = (int)(ls[4] | (ls[5] << 16)); pl.w = (int)(ls[6] | (ls[7] << 16));
  *(int4*)(w1s + o)             = ph;
  *(int4*)(w1s + o + PLANE)     = pm;
  *(int4*)(w1s + o + 2 * PLANE) = pl;
}

// ---------------- Kernel 1: masked LayerNorm stats (mu, rstd per row) -------
__global__ __launch_bounds__(256) void ln_stats_k(
    const float* __restrict__ emb, const float* __restrict__ attn,
    float* __restrict__ mu, float* __restrict__ rstd) {
  int row = blockIdx.x * 4 + (threadIdx.x >> 6);
  int lane = threadIdx.x & 63;
  float a = attn[row];
  const float4* e = (const float4*)(emb + (size_t)row * Dc);
  float4 v0 = e[lane], v1 = e[lane + 64], v2 = e[lane + 128];
  float x[12] = {v0.x*a, v0.y*a, v0.z*a, v0.w*a,
                 v1.x*a, v1.y*a, v1.z*a, v1.w*a,
                 v2.x*a, v2.y*a, v2.z*a, v2.w*a};
  float s = 0.f;
  #pragma unroll
  for (int i = 0; i < 12; i++) s += x[i];
  #pragma unroll
  for (int o = 32; o; o >>= 1) s += __shfl_xor(s, o);
  float m = s / 768.0f;
  float q = 0.f;
  #pragma unroll
  for (int i = 0; i < 12; i++) { float d = x[i] - m; q += d * d; }
  #pragma unroll
  for (int o = 32; o; o >>= 1) q += __shfl_xor(q, o);
  float var = q / 768.0f;
  if (lane == 0) { mu[row] = m; rstd[row] = 1.0f / sqrtf(var + 1e-5f); }
}

// ---- Kernel 2: full-H MFMA GEMM. 64 rows/block, 8 waves (2M x 4N), each ----
// wave 32 rows x 256 cols in registers. B fragments loaded directly from the
// pre-split W1 planes (L2). A: LN+split3 staged once per K-step, dbuf LDS.
__global__ __launch_bounds__(512, 2) void gemm_scores_mfma2(
    const float* __restrict__ emb, const float* __restrict__ attn,
    const float* __restrict__ ln_g, const float* __restrict__ ln_b,
    const ushort* __restrict__ w1s, const float* __restrict__ b1,
    const float* __restrict__ W2, const float* __restrict__ b2,
    const float* __restrict__ mu, const float* __restrict__ rstd,
    float* __restrict__ scores) {
  __shared__ int4 Abuf[2][3][4][64];   // 24 KB: [buf][split][kg][row] 16B
  __shared__ float gls[768], bls[768]; // 6 KB
  __shared__ float red[4][64];         // 1 KB
  const int base = blockIdx.x * 64;
  if (attn[base] == 0.0f) return;      // attn is a prefix mask
  const int t = threadIdx.x;
  const int lane = t & 63;
  const int lrow = lane & 31;
  const int lkg = lane >> 5;
  const int w = t >> 6, wm = w >> 2, wn = w & 3;

  if (t < 192) {
    *(float4*)&gls[t * 4] = *(const float4*)&ln_g[t * 4];
    *(float4*)&bls[t * 4] = *(const float4*)&ln_b[t * 4];
  }
  // staging identity: 512 threads cover 64 rows x 4 kg x 2 half-chunks
  const int srow = t & 63;
  const int skg = (t >> 6) & 3;
  const int ssub = t >> 8;             // 0/1
  const int skoff = skg * 8 + ssub * 4;
  const float la  = attn[base + srow];
  const float lmu = mu[base + srow];
  const float lrs = rstd[base + srow];
  const float* erow = emb + (size_t)(base + srow) * Dc + skoff;

  f32x16 acc[8];
  #pragma unroll
  for (int nt = 0; nt < 8; nt++)
    #pragma unroll
    for (int r = 0; r < 16; r++) acc[nt][r] = 0.f;

  __syncthreads();  // gls/bls visible
  // ---- prologue: stage k0=0 into buf 0 ----
  {
    float4 ev = *(const float4*)(erow);
    float4 gv = *(const float4*)&gls[skoff];
    float4 bv = *(const float4*)&bls[skoff];
    float xs[4] = {ev.x, ev.y, ev.z, ev.w};
    float gs[4] = {gv.x, gv.y, gv.z, gv.w};
    float bs[4] = {bv.x, bv.y, bv.z, bv.w};
    unsigned hh[4], hm[4], hl[4];
    #pragma unroll
    for (int e = 0; e < 4; e++) {
      float xn = (xs[e] * la - lmu) * lrs * gs[e] + bs[e];
      split3(xn, hh[e], hm[e], hl[e]);
    }
    char* bw = (char*)&Abuf[0][0][skg][srow] + ssub * 8;
    *(int2*)bw          = make_int2((int)(hh[0] | (hh[1] << 16)), (int)(hh[2] | (hh[3] << 16)));
    *(int2*)(bw + 4096) = make_int2((int)(hm[0] | (hm[1] << 16)), (int)(hm[2] | (hm[3] << 16)));
    *(int2*)(bw + 8192) = make_int2((int)(hl[0] | (hl[1] << 16)), (int)(hl[2] | (hl[3] << 16)));
  }
  __syncthreads();

  #pragma unroll 1
  for (int i = 0; i < 24; i++) {
    const int p = i & 1;
    const bool more = (i < 23);
    float4 evn;
    if (more) evn = *(const float4*)(erow + (i + 1) * 32);  // early issue
    #pragma unroll 1
    for (int kh = 0; kh < 2; kh++) {
      bf16x8 af0 = *(const bf16x8*)&Abuf[p][0][kh * 2 + lkg][wm * 32 + lrow];
      bf16x8 af1 = *(const bf16x8*)&Abuf[p][1][kh * 2 + lkg][wm * 32 + lrow];
      bf16x8 af2 = *(const bf16x8*)&Abuf[p][2][kh * 2 + lkg][wm * 32 + lrow];
      const size_t kgg = (size_t)(i * 4 + kh * 2 + lkg);
      const ushort* bp0 = w1s + (kgg * 1024 + wn * 256 + lrow) * 8;
      #pragma unroll
      for (int nt = 0; nt < 8; nt++) {
        const ushort* bp = bp0 + nt * 256;   // 32 cols * 8
        bf16x8 bh = *(const bf16x8*)(bp);
        bf16x8 bm = *(const bf16x8*)(bp + PLANE);
        bf16x8 bl = *(const bf16x8*)(bp + 2 * PLANE);
        acc[nt] = __builtin_amdgcn_mfma_f32_32x32x16_bf16(af0, bh, acc[nt], 0, 0, 0);
        acc[nt] = __builtin_amdgcn_mfma_f32_32x32x16_bf16(af0, bm, acc[nt], 0, 0, 0);
        acc[nt] = __builtin_amdgcn_mfma_f32_32x32x16_bf16(af1, bh, acc[nt], 0, 0, 0);
        acc[nt] = __builtin_amdgcn_mfma_f32_32x32x16_bf16(af1, bm, acc[nt], 0, 0, 0);
        acc[nt] = __builtin_amdgcn_mfma_f32_32x32x16_bf16(af0, bl, acc[nt], 0, 0, 0);
        acc[nt] = __builtin_amdgcn_mfma_f32_32x32x16_bf16(af2, bh, acc[nt], 0, 0, 0);
      }
    }
    if (more) {
      const int koff = (i + 1) * 32 + skoff;
      float4 gv = *(const float4*)&gls[koff];
      float4 bv = *(const float4*)&bls[koff];
      float xs[4] = {evn.x, evn.y, evn.z, evn.w};
      float gs[4] = {gv.x, gv.y, gv.z, gv.w};
      float bs[4] = {bv.x, bv.y, bv.z, bv.w};
      unsigned hh[4], hm[4], hl[4];
      #pragma unroll
      for (int e = 0; e < 4; e++) {
        float xn = (xs[e] * la - lmu) * lrs * gs[e] + bs[e];
        split3(xn, hh[e], hm[e], hl[e]);
      }
      char* bw = (char*)&Abuf[p ^ 1][0][skg][srow] + ssub * 8;
      *(int2*)bw          = make_int2((int)(hh[0] | (hh[1] << 16)), (int)(hh[2] | (hh[3] << 16)));
      *(int2*)(bw + 4096) = make_int2((int)(hm[0] | (hm[1] << 16)), (int)(hm[2] | (hm[3] << 16)));
      *(int2*)(bw + 8192) = make_int2((int)(hl[0] | (hl[1] << 16)), (int)(hl[2] | (hl[3] << 16)));
    }
    __syncthreads();
  }

  // ---- epilogue: bias + erf-gelu + W2 dot, reduce 32 lanes + 4 N-waves ----
  float sacc[16];
  #pragma unroll
  for (int r = 0; r < 16; r++) sacc[r] = 0.f;
  #pragma unroll
  for (int nt = 0; nt < 8; nt++) {
    const int col = wn * 256 + nt * 32 + lrow;
    const float b1v = b1[col];
    const float w2v = W2[col];
    #pragma unroll
    for (int r = 0; r < 16; r++)
      sacc[r] += gelu_erf(acc[nt][r] + b1v) * w2v;
  }
  #pragma unroll
  for (int r = 0; r < 16; r++) {
    float v = sacc[r];
    v += __shfl_xor(v, 1);  v += __shfl_xor(v, 2);  v += __shfl_xor(v, 4);
    v += __shfl_xor(v, 8);  v += __shfl_xor(v, 16);
    if (lrow == 0) {
      int row = wm * 32 + (r & 3) + 8 * (r >> 2) + 4 * lkg;
      red[wn][row] = v;
    }
  }
  __syncthreads();
  if (t < 64)
    scores[base + t] = red[0][t] + red[1][t] + red[2][t] + red[3][t] + b2[0];
}

// ---- Kernel 3: 1.5-entmax (f64 tau), exact stable ranking, h-mask writes ---
__global__ __launch_bounds__(256) void entmax_rank_k(
    const float* __restrict__ scores, const float* __restrict__ attn,
    float* __restrict__ out) {
  const int N = 4096;
  __shared__ unsigned long long keys[4096];
  __shared__ double tsum[256], tsq[256];
  __shared__ int tcnt[256];
  __shared__ float sred[4];
  __shared__ double sh_tau;
  __shared__ int sh_S, sh_m, sh_k[5];
  const int b = blockIdx.x;
  const int t = threadIdx.x;
  const float* srow = scores + b * N;
  const float* arow = attn + b * N;
  float teff_l = 0.f;
  for (int i = t; i < N; i += 256) {
    float a = arow[i];
    float s = srow[i];
    float xe = (a == 0.f) ? -1e9f : s;
    teff_l += a;
    keys[i] = ((unsigned long long)f2o(xe) << 32) |
              (unsigned long long)(0xFFFFFFFFu - (unsigned)i);
  }
  #pragma unroll
  for (int o = 32; o; o >>= 1) teff_l += __shfl_xor(teff_l, o);
  if ((t & 63) == 0) sred[t >> 6] = teff_l;
  __syncthreads();
  if (t == 0) {
    float te = sred[0] + sred[1] + sred[2] + sred[3];
    const float rh[5] = {0.1f, 0.3f, 0.5f, 0.7f, 0.9f};
    for (int r = 0; r < 5; r++) {
      int ki = (int)floorf(rh[r] * te);   // must be f32 math
      sh_k[r] = ki < 1 ? 1 : ki;
    }
  }
  for (int kk = 2; kk <= N; kk <<= 1) {
    for (int j = kk >> 1; j > 0; j >>= 1) {
      __syncthreads();
      for (int idx = t; idx < N / 2; idx += 256) {
        int i = 2 * idx - (idx & (j - 1));
        int l = i | j;
        unsigned long long A = keys[i], Bv = keys[l];
        bool up = ((i & kk) == 0);
        if (up ? (A < Bv) : (A > Bv)) { keys[i] = Bv; keys[l] = A; }
      }
    }
  }
  __syncthreads();
  const int base = t * 16;
  {
    double ls = 0, lq = 0;
    for (int ii = 0; ii < 16; ii++) {
      double x = 0.5 * (double)o2f((unsigned)(keys[base + ii] >> 32));
      ls += x; lq += x * x;
    }
    tsum[t] = ls; tsq[t] = lq;
  }
  __syncthreads();
  if (t == 0) {
    double rs = 0, rq = 0;
    for (int i = 0; i < 256; i++) {
      double a = tsum[i], c = tsq[i];
      tsum[i] = rs; tsq[i] = rq; rs += a; rq += c;
    }
  }
  __syncthreads();
  {
    double cs = tsum[t], cq = tsq[t];
    int lc = 0;
    for (int ii = 0; ii < 16; ii++) {
      double x = 0.5 * (double)o2f((unsigned)(keys[base + ii] >> 32));
      cs += x; cq += x * x;
      double rho = (double)(base + ii + 1);
      double mean = cs / rho, msq = cq / rho;
      double ss = rho * (msq - mean * mean);
      double delta = (1.0 - ss) / rho;
      double dl = delta > 0.0 ? delta : 0.0;
      double tau = mean - sqrt(dl);
      if (tau <= x) lc++;
    }
    tcnt[t] = lc;
  }
  __syncthreads();
  if (t == 0) {
    int r = 0;
    for (int i = 0; i < 256; i++) { int c = tcnt[i]; tcnt[i] = r; r += c; }
    sh_S = r;
  }
  __syncthreads();
  {
    int jstar = sh_S - 1;
    if (jstar >= base && jstar < base + 16) {
      double cs = tsum[t], cq = tsq[t], tau = 0.0;
      for (int ii = 0; ii <= jstar - base; ii++) {
        double x = 0.5 * (double)o2f((unsigned)(keys[base + ii] >> 32));
        cs += x; cq += x * x;
        double rho = (double)(base + ii + 1);
        double mean = cs / rho, msq = cq / rho;
        double ss = rho * (msq - mean * mean);
        double delta = (1.0 - ss) / rho;
        double dl = delta > 0.0 ? delta : 0.0;
        tau = mean - sqrt(dl);
      }
      sh_tau = tau;
    }
  }
  __syncthreads();
  const double tau = sh_tau;
  float ps[16], pa[16];
  {
    int lf = 0;
    for (int ii = 0; ii < 16; ii++) {
      int p = base + ii;
      ps[ii] = srow[p]; pa[ii] = arow[p];
      double d = 0.5 * (double)ps[ii] - tau;
      if (pa[ii] != 0.f && d > 0.0) lf++;
    }
    tcnt[t] = lf;
  }
  __syncthreads();
  if (t == 0) {
    int r = 0;
    for (int i = 0; i < 256; i++) { int c = tcnt[i]; tcnt[i] = r; r += c; }
    sh_m = r;
  }
  __syncthreads();
  const int m = sh_m;
  const int k0_ = sh_k[0], k1_ = sh_k[1], k2_ = sh_k[2], k3_ = sh_k[3], k4_ = sh_k[4];
  {
    int cex = tcnt[t];
    for (int ii = 0; ii < 16; ii++) {
      int p = base + ii;
      double d = 0.5 * (double)ps[ii] - tau;
      bool av = (pa[ii] != 0.f);
      bool sup = av && (d > 0.0);
      out[b * N + p] = sup ? (float)(d * d) : 0.0f;
      if (!sup) {
        int rank = m + p - cex;
        out[1 * BTc + b * N + p] = (av && rank < k0_) ? 1.f : 0.f;
        out[2 * BTc + b * N + p] = (av && rank < k1_) ? 1.f : 0.f;
        out[3 * BTc + b * N + p] = (av && rank < k2_) ? 1.f : 0.f;
        out[4 * BTc + b * N + p] = (av && rank < k3_) ? 1.f : 0.f;
        out[5 * BTc + b * N + p] = (av && rank < k4_) ? 1.f : 0.f;
      } else {
        cex++;
      }
    }
  }
  for (int r = t; r < m; r += 256) {
    int i = (int)(0xFFFFFFFFu - (unsigned)(keys[r] & 0xFFFFFFFFull));
    out[1 * BTc + b * N + i] = (r < k0_) ? 1.f : 0.f;
    out[2 * BTc + b * N + i] = (r < k1_) ? 1.f : 0.f;
    out[3 * BTc + b * N + i] = (r < k2_) ? 1.f : 0.f;
    out[4 * BTc + b * N + i] = (r < k3_) ? 1.f : 0.f;
    out[5 * BTc + b * N + i] = (r < k4_) ? 1.f : 0.f;
  }
}

extern "C" void kernel_launch(void* const* d_in, const int* in_sizes, int n_in,
                              void* d_out, int out_size, void* d_ws, size_t ws_size,
                              hipStream_t stream) {
  (void)in_sizes; (void)n_in; (void)out_size; (void)ws_size;
  const float* emb  = (const float*)d_in[0];
  const float* attn = (const float*)d_in[1];
  const float* ln_g = (const float*)d_in[2];
  const float* ln_b = (const float*)d_in[3];
  const float* W1   = (const float*)d_in[4];
  const float* b1   = (const float*)d_in[5];
  const float* W2   = (const float*)d_in[6];
  const float* b2   = (const float*)d_in[7];
  float* out = (float*)d_out;
  float* wsf = (float*)d_ws;
  float* mu     = wsf;
  float* rstd   = wsf + BTc;
  float* scores = wsf + 2 * BTc;
  ushort* w1s   = (ushort*)(wsf + 3 * BTc);  // 3 planes * 1.5 MB

  w1_split_k<<<384, 256, 0, stream>>>(W1, w1s);
  ln_stats_k<<<BTc / 4, 256, 0, stream>>>(emb, attn, mu, rstd);
  gemm_scores_mfma2<<<BTc / 64, 512, 0, stream>>>(
      emb, attn, ln_g, ln_b, w1s, b1, W2, b2, mu, rstd, scores);
  entmax_rank_k<<<Bc, 256, 0, stream>>>(scores, attn, out);
}

// Round 4
// 1543.270 us; speedup vs baseline: 1.6576x; 1.0278x over previous
//
#include <hip/hip_runtime.h>
#include <math.h>

#define Bc 32
#define Tc 4096
#define Dc 768
#define Hc 1024
#define BTc (Bc*Tc)
#define PLANE 786432   // 96*1024*8 ushorts per split plane

typedef __bf16 bf16x8 __attribute__((ext_vector_type(8)));
typedef float f32x16 __attribute__((ext_vector_type(16)));

__device__ __forceinline__ float gelu_erf(float x) {
  return 0.5f * x * (1.0f + erff(x * 0.70710678118654752440f));
}
__device__ __forceinline__ unsigned bf16rne(float x) {
  unsigned u = __float_as_uint(x);
  return (u + 0x7FFFu + ((u >> 16) & 1u)) >> 16;
}
// exact 3-way bf16 split: x ~= hi+mid+lo, residual ~2^-27 |x|
__device__ __forceinline__ void split3(float x, unsigned& h, unsigned& m, unsigned& l) {
  h = bf16rne(x);
  float r1 = x - __uint_as_float(h << 16);
  m = bf16rne(r1);
  float r2 = r1 - __uint_as_float(m << 16);
  l = bf16rne(r2);
}
__device__ __forceinline__ unsigned f2o(float f) {
  unsigned b = __float_as_uint(f);
  return (b & 0x80000000u) ? ~b : (b | 0x80000000u);
}
__device__ __forceinline__ float o2f(unsigned o) {
  unsigned b = (o & 0x80000000u) ? (o & 0x7FFFFFFFu) : ~o;
  return __uint_as_float(b);
}

// ---------------- Kernel 0: pre-split W1 into 3 bf16 planes -----------------
// layout: w1s[s*PLANE + (kg*1024 + n)*8 + j]  for element (k=kg*8+j, n)
__global__ __launch_bounds__(256) void w1_split_k(
    const float* __restrict__ W1, ushort* __restrict__ w1s) {
  int id = blockIdx.x * 256 + threadIdx.x;   // 96*1024 total
  int n = id & 1023, kg = id >> 10;
  unsigned hs[8], ms[8], ls[8];
  #pragma unroll
  for (int j = 0; j < 8; j++) {
    float x = W1[(size_t)(kg * 8 + j) * Hc + n];
    split3(x, hs[j], ms[j], ls[j]);
  }
  size_t o = ((size_t)kg * 1024 + n) * 8;
  int4 ph, pm, pl;
  ph.x = (int)(hs[0] | (hs[1] << 16)); ph.y = (int)(hs[2] | (hs[3] << 16));
  ph.z = (int)(hs[4] | (hs[5] << 16)); ph.w = (int)(hs[6] | (hs[7] << 16));
  pm.x = (int)(ms[0] | (ms[1] << 16)); pm.y = (int)(ms[2] | (ms[3] << 16));
  pm.z = (int)(ms[4] | (ms[5] << 16)); pm.w = (int)(ms[6] | (ms[7] << 16));
  pl.x = (int)(ls[0] | (ls[1] << 16)); pl.y = (int)(ls[2] | (ls[3] << 16));
  pl.z = (int)(ls[4] | (ls[5] << 16)); pl.w = (int)(ls[6] | (ls[7] << 16));
  *(int4*)(w1s + o)             = ph;
  *(int4*)(w1s + o + PLANE)     = pm;
  *(int4*)(w1s + o + 2 * PLANE) = pl;
}

// ---------------- Kernel 1: masked LayerNorm stats (mu, rstd per row) -------
__global__ __launch_bounds__(256) void ln_stats_k(
    const float* __restrict__ emb, const float* __restrict__ attn,
    float* __restrict__ mu, float* __restrict__ rstd) {
  int row = blockIdx.x * 4 + (threadIdx.x >> 6);
  int lane = threadIdx.x & 63;
  float a = attn[row];
  const float4* e = (const float4*)(emb + (size_t)row * Dc);
  float4 v0 = e[lane], v1 = e[lane + 64], v2 = e[lane + 128];
  float x[12] = {v0.x*a, v0.y*a, v0.z*a, v0.w*a,
                 v1.x*a, v1.y*a, v1.z*a, v1.w*a,
                 v2.x*a, v2.y*a, v2.z*a, v2.w*a};
  float s = 0.f;
  #pragma unroll
  for (int i = 0; i < 12; i++) s += x[i];
  #pragma unroll
  for (int o = 32; o; o >>= 1) s += __shfl_xor(s, o);
  float m = s / 768.0f;
  float q = 0.f;
  #pragma unroll
  for (int i = 0; i < 12; i++) { float d = x[i] - m; q += d * d; }
  #pragma unroll
  for (int o = 32; o; o >>= 1) q += __shfl_xor(q, o);
  float var = q / 768.0f;
  if (lane == 0) { mu[row] = m; rstd[row] = 1.0f / sqrtf(var + 1e-5f); }
}

// ---- Kernel 2: full-H MFMA GEMM. 64 rows/block, 8 waves (2M x 4N), each ----
// wave 32 rows x 256 cols in registers (acc = 128 VGPR -> needs the 256-VGPR
// budget: __launch_bounds__(512,1), 1 block/CU, 2 waves/SIMD, NO SPILL).
// B fragments straight from pre-split W1 planes (L2/L3). A: LN+split3 staged
// by waves 0-3 only, 8 k-elems/thread -> b128 conflict-free LDS writes.
__global__ __launch_bounds__(512, 1) void gemm_scores_mfma2(
    const float* __restrict__ emb, const float* __restrict__ attn,
    const float* __restrict__ ln_g, const float* __restrict__ ln_b,
    const ushort* __restrict__ w1s, const float* __restrict__ b1,
    const float* __restrict__ W2, const float* __restrict__ b2,
    const float* __restrict__ mu, const float* __restrict__ rstd,
    float* __restrict__ scores) {
  __shared__ int4 Abuf[2][3][4][64];   // 24 KB: [buf][split][kg][row] 16B
  __shared__ float gls[768], bls[768]; // 6 KB
  __shared__ float red[4][64];         // 1 KB
  const int base = blockIdx.x * 64;
  if (attn[base] == 0.0f) return;      // attn is a prefix mask
  const int t = threadIdx.x;
  const int lane = t & 63;
  const int lrow = lane & 31;
  const int lkg = lane >> 5;
  const int w = t >> 6, wm = w >> 2, wn = w & 3;

  if (t < 192) {
    *(float4*)&gls[t * 4] = *(const float4*)&ln_g[t * 4];
    *(float4*)&bls[t * 4] = *(const float4*)&ln_b[t * 4];
  }
  // staging identity (waves 0-3): 256 threads cover 64 rows x 4 kg, 8 k each
  const bool stager = (t < 256);
  const int srow = t & 63;
  const int skg = (t >> 6) & 3;
  const int skoff = skg * 8;
  const float la  = attn[base + srow];
  const float lmu = mu[base + srow];
  const float lrs = rstd[base + srow];
  const float* erow = emb + (size_t)(base + srow) * Dc + skoff;

  f32x16 acc[8];
  #pragma unroll
  for (int nt = 0; nt < 8; nt++)
    #pragma unroll
    for (int r = 0; r < 16; r++) acc[nt][r] = 0.f;

  __syncthreads();  // gls/bls visible
  // ---- prologue: stage k0=0 into buf 0 ----
  if (stager) {
    float4 e0 = *(const float4*)(erow);
    float4 e1 = *(const float4*)(erow + 4);
    float4 g0 = *(const float4*)&gls[skoff];
    float4 g1 = *(const float4*)&gls[skoff + 4];
    float4 q0 = *(const float4*)&bls[skoff];
    float4 q1 = *(const float4*)&bls[skoff + 4];
    float xs[8] = {e0.x,e0.y,e0.z,e0.w,e1.x,e1.y,e1.z,e1.w};
    float gs[8] = {g0.x,g0.y,g0.z,g0.w,g1.x,g1.y,g1.z,g1.w};
    float bs[8] = {q0.x,q0.y,q0.z,q0.w,q1.x,q1.y,q1.z,q1.w};
    unsigned hh[8], hm[8], hl[8];
    #pragma unroll
    for (int e = 0; e < 8; e++) {
      float xn = (xs[e] * la - lmu) * lrs * gs[e] + bs[e];
      split3(xn, hh[e], hm[e], hl[e]);
    }
    int4 ph, pm, pl;
    ph.x = (int)(hh[0] | (hh[1] << 16)); ph.y = (int)(hh[2] | (hh[3] << 16));
    ph.z = (int)(hh[4] | (hh[5] << 16)); ph.w = (int)(hh[6] | (hh[7] << 16));
    pm.x = (int)(hm[0] | (hm[1] << 16)); pm.y = (int)(hm[2] | (hm[3] << 16));
    pm.z = (int)(hm[4] | (hm[5] << 16)); pm.w = (int)(hm[6] | (hm[7] << 16));
    pl.x = (int)(hl[0] | (hl[1] << 16)); pl.y = (int)(hl[2] | (hl[3] << 16));
    pl.z = (int)(hl[4] | (hl[5] << 16)); pl.w = (int)(hl[6] | (hl[7] << 16));
    Abuf[0][0][skg][srow] = ph;
    Abuf[0][1][skg][srow] = pm;
    Abuf[0][2][skg][srow] = pl;
  }
  __syncthreads();

  #pragma unroll 1
  for (int i = 0; i < 24; i++) {
    const int p = i & 1;
    const bool more = (i < 23);
    float4 evn0, evn1;
    if (stager && more) {            // early issue of next emb chunk
      evn0 = *(const float4*)(erow + (i + 1) * 32);
      evn1 = *(const float4*)(erow + (i + 1) * 32 + 4);
    }
    #pragma unroll 1
    for (int kh = 0; kh < 2; kh++) {
      bf16x8 af0 = *(const bf16x8*)&Abuf[p][0][kh * 2 + lkg][wm * 32 + lrow];
      bf16x8 af1 = *(const bf16x8*)&Abuf[p][1][kh * 2 + lkg][wm * 32 + lrow];
      bf16x8 af2 = *(const bf16x8*)&Abuf[p][2][kh * 2 + lkg][wm * 32 + lrow];
      const size_t kgg = (size_t)(i * 4 + kh * 2 + lkg);
      const ushort* bp0 = w1s + (kgg * 1024 + wn * 256 + lrow) * 8;
      #pragma unroll
      for (int nt = 0; nt < 8; nt++) {
        const ushort* bp = bp0 + nt * 256;   // 32 cols * 8
        bf16x8 bh = *(const bf16x8*)(bp);
        bf16x8 bm = *(const bf16x8*)(bp + PLANE);
        bf16x8 bl = *(const bf16x8*)(bp + 2 * PLANE);
        acc[nt] = __builtin_amdgcn_mfma_f32_32x32x16_bf16(af0, bh, acc[nt], 0, 0, 0);
        acc[nt] = __builtin_amdgcn_mfma_f32_32x32x16_bf16(af0, bm, acc[nt], 0, 0, 0);
        acc[nt] = __builtin_amdgcn_mfma_f32_32x32x16_bf16(af1, bh, acc[nt], 0, 0, 0);
        acc[nt] = __builtin_amdgcn_mfma_f32_32x32x16_bf16(af1, bm, acc[nt], 0, 0, 0);
        acc[nt] = __builtin_amdgcn_mfma_f32_32x32x16_bf16(af0, bl, acc[nt], 0, 0, 0);
        acc[nt] = __builtin_amdgcn_mfma_f32_32x32x16_bf16(af2, bh, acc[nt], 0, 0, 0);
      }
    }
    if (stager && more) {
      const int koff = (i + 1) * 32 + skoff;
      float4 g0 = *(const float4*)&gls[koff];
      float4 g1 = *(const float4*)&gls[koff + 4];
      float4 q0 = *(const float4*)&bls[koff];
      float4 q1 = *(const float4*)&bls[koff + 4];
      float xs[8] = {evn0.x,evn0.y,evn0.z,evn0.w,evn1.x,evn1.y,evn1.z,evn1.w};
      float gs[8] = {g0.x,g0.y,g0.z,g0.w,g1.x,g1.y,g1.z,g1.w};
      float bs[8] = {q0.x,q0.y,q0.z,q0.w,q1.x,q1.y,q1.z,q1.w};
      unsigned hh[8], hm[8], hl[8];
      #pragma unroll
      for (int e = 0; e < 8; e++) {
        float xn = (xs[e] * la - lmu) * lrs * gs[e] + bs[e];
        split3(xn, hh[e], hm[e], hl[e]);
      }
      int4 ph, pm, pl;
      ph.x = (int)(hh[0] | (hh[1] << 16)); ph.y = (int)(hh[2] | (hh[3] << 16));
      ph.z = (int)(hh[4] | (hh[5] << 16)); ph.w = (int)(hh[6] | (hh[7] << 16));
      pm.x = (int)(hm[0] | (hm[1] << 16)); pm.y = (int)(hm[2] | (hm[3] << 16));
      pm.z = (int)(hm[4] | (hm[5] << 16)); pm.w = (int)(hm[6] | (hm[7] << 16));
      pl.x = (int)(hl[0] | (hl[1] << 16)); pl.y = (int)(hl[2] | (hl[3] << 16));
      pl.z = (int)(hl[4] | (hl[5] << 16)); pl.w = (int)(hl[6] | (hl[7] << 16));
      Abuf[p ^ 1][0][skg][srow] = ph;
      Abuf[p ^ 1][1][skg][srow] = pm;
      Abuf[p ^ 1][2][skg][srow] = pl;
    }
    __syncthreads();
  }

  // ---- epilogue: bias + erf-gelu + W2 dot, reduce 32 lanes + 4 N-waves ----
  float sacc[16];
  #pragma unroll
  for (int r = 0; r < 16; r++) sacc[r] = 0.f;
  #pragma unroll
  for (int nt = 0; nt < 8; nt++) {
    const int col = wn * 256 + nt * 32 + lrow;
    const float b1v = b1[col];
    const float w2v = W2[col];
    #pragma unroll
    for (int r = 0; r < 16; r++)
      sacc[r] += gelu_erf(acc[nt][r] + b1v) * w2v;
  }
  #pragma unroll
  for (int r = 0; r < 16; r++) {
    float v = sacc[r];
    v += __shfl_xor(v, 1);  v += __shfl_xor(v, 2);  v += __shfl_xor(v, 4);
    v += __shfl_xor(v, 8);  v += __shfl_xor(v, 16);
    if (lrow == 0) {
      int row = wm * 32 + (r & 3) + 8 * (r >> 2) + 4 * lkg;
      red[wn][row] = v;
    }
  }
  __syncthreads();
  if (t < 64)
    scores[base + t] = red[0][t] + red[1][t] + red[2][t] + red[3][t] + b2[0];
}

// ---- Kernel 3: 1.5-entmax (f64 tau), exact stable ranking, h-mask writes ---
__global__ __launch_bounds__(256) void entmax_rank_k(
    const float* __restrict__ scores, const float* __restrict__ attn,
    float* __restrict__ out) {
  const int N = 4096;
  __shared__ unsigned long long keys[4096];
  __shared__ double tsum[256], tsq[256];
  __shared__ int tcnt[256];
  __shared__ float sred[4];
  __shared__ double sh_tau;
  __shared__ int sh_S, sh_m, sh_k[5];
  const int b = blockIdx.x;
  const int t = threadIdx.x;
  const float* srow = scores + b * N;
  const float* arow = attn + b * N;
  float teff_l = 0.f;
  for (int i = t; i < N; i += 256) {
    float a = arow[i];
    float s = srow[i];
    float xe = (a == 0.f) ? -1e9f : s;
    teff_l += a;
    keys[i] = ((unsigned long long)f2o(xe) << 32) |
              (unsigned long long)(0xFFFFFFFFu - (unsigned)i);
  }
  #pragma unroll
  for (int o = 32; o; o >>= 1) teff_l += __shfl_xor(teff_l, o);
  if ((t & 63) == 0) sred[t >> 6] = teff_l;
  __syncthreads();
  if (t == 0) {
    float te = sred[0] + sred[1] + sred[2] + sred[3];
    const float rh[5] = {0.1f, 0.3f, 0.5f, 0.7f, 0.9f};
    for (int r = 0; r < 5; r++) {
      int ki = (int)floorf(rh[r] * te);   // must be f32 math
      sh_k[r] = ki < 1 ? 1 : ki;
    }
  }
  for (int kk = 2; kk <= N; kk <<= 1) {
    for (int j = kk >> 1; j > 0; j >>= 1) {
      __syncthreads();
      for (int idx = t; idx < N / 2; idx += 256) {
        int i = 2 * idx - (idx & (j - 1));
        int l = i | j;
        unsigned long long A = keys[i], Bv = keys[l];
        bool up = ((i & kk) == 0);
        if (up ? (A < Bv) : (A > Bv)) { keys[i] = Bv; keys[l] = A; }
      }
    }
  }
  __syncthreads();
  const int base = t * 16;
  {
    double ls = 0, lq = 0;
    for (int ii = 0; ii < 16; ii++) {
      double x = 0.5 * (double)o2f((unsigned)(keys[base + ii] >> 32));
      ls += x; lq += x * x;
    }
    tsum[t] = ls; tsq[t] = lq;
  }
  __syncthreads();
  if (t == 0) {
    double rs = 0, rq = 0;
    for (int i = 0; i < 256; i++) {
      double a = tsum[i], c = tsq[i];
      tsum[i] = rs; tsq[i] = rq; rs += a; rq += c;
    }
  }
  __syncthreads();
  {
    double cs = tsum[t], cq = tsq[t];
    int lc = 0;
    for (int ii = 0; ii < 16; ii++) {
      double x = 0.5 * (double)o2f((unsigned)(keys[base + ii] >> 32));
      cs += x; cq += x * x;
      double rho = (double)(base + ii + 1);
      double mean = cs / rho, msq = cq / rho;
      double ss = rho * (msq - mean * mean);
      double delta = (1.0 - ss) / rho;
      double dl = delta > 0.0 ? delta : 0.0;
      double tau = mean - sqrt(dl);
      if (tau <= x) lc++;
    }
    tcnt[t] = lc;
  }
  __syncthreads();
  if (t == 0) {
    int r = 0;
    for (int i = 0; i < 256; i++) { int c = tcnt[i]; tcnt[i] = r; r += c; }
    sh_S = r;
  }
  __syncthreads();
  {
    int jstar = sh_S - 1;
    if (jstar >= base && jstar < base + 16) {
      double cs = tsum[t], cq = tsq[t], tau = 0.0;
      for (int ii = 0; ii <= jstar - base; ii++) {
        double x = 0.5 * (double)o2f((unsigned)(keys[base + ii] >> 32));
        cs += x; cq += x * x;
        double rho = (double)(base + ii + 1);
        double mean = cs / rho, msq = cq / rho;
        double ss = rho * (msq - mean * mean);
        double delta = (1.0 - ss) / rho;
        double dl = delta > 0.0 ? delta : 0.0;
        tau = mean - sqrt(dl);
      }
      sh_tau = tau;
    }
  }
  __syncthreads();
  const double tau = sh_tau;
  float ps[16], pa[16];
  {
    int lf = 0;
    for (int ii = 0; ii < 16; ii++) {
      int p = base + ii;
      ps[ii] = srow[p]; pa[ii] = arow[p];
      double d = 0.5 * (double)ps[ii] - tau;
      if (pa[ii] != 0.f && d > 0.0) lf++;
    }
    tcnt[t] = lf;
  }
  __syncthreads();
  if (t == 0) {
    int r = 0;
    for (int i = 0; i < 256; i++) { int c = tcnt[i]; tcnt[i] = r; r += c; }
    sh_m = r;
  }
  __syncthreads();
  const int m = sh_m;
  const int k0_ = sh_k[0], k1_ = sh_k[1], k2_ = sh_k[2], k3_ = sh_k[3], k4_ = sh_k[4];
  {
    int cex = tcnt[t];
    for (int ii = 0; ii < 16; ii++) {
      int p = base + ii;
      double d = 0.5 * (double)ps[ii] - tau;
      bool av = (pa[ii] != 0.f);
      bool sup = av && (d > 0.0);
      out[b * N + p] = sup ? (float)(d * d) : 0.0f;
      if (!sup) {
        int rank = m + p - cex;
        out[1 * BTc + b * N + p] = (av && rank < k0_) ? 1.f : 0.f;
        out[2 * BTc + b * N + p] = (av && rank < k1_) ? 1.f : 0.f;
        out[3 * BTc + b * N + p] = (av && rank < k2_) ? 1.f : 0.f;
        out[4 * BTc + b * N + p] = (av && rank < k3_) ? 1.f : 0.f;
        out[5 * BTc + b * N + p] = (av && rank < k4_) ? 1.f : 0.f;
      } else {
        cex++;
      }
    }
  }
  for (int r = t; r < m; r += 256) {
    int i = (int)(0xFFFFFFFFu - (unsigned)(keys[r] & 0xFFFFFFFFull));
    out[1 * BTc + b * N + i] = (r < k0_) ? 1.f : 0.f;
    out[2 * BTc + b * N + i] = (r < k1_) ? 1.f : 0.f;
    out[3 * BTc + b * N + i] = (r < k2_) ? 1.f : 0.f;
    out[4 * BTc + b * N + i] = (r < k3_) ? 1.f : 0.f;
    out[5 * BTc + b * N + i] = (r < k4_) ? 1.f : 0.f;
  }
}

extern "C" void kernel_launch(void* const* d_in, const int* in_sizes, int n_in,
                              void* d_out, int out_size, void* d_ws, size_t ws_size,
                              hipStream_t stream) {
  (void)in_sizes; (void)n_in; (void)out_size; (void)ws_size;
  const float* emb  = (const float*)d_in[0];
  const float* attn = (const float*)d_in[1];
  const float* ln_g = (const float*)d_in[2];
  const float* ln_b = (const float*)d_in[3];
  const float* W1   = (const float*)d_in[4];
  const float* b1   = (const float*)d_in[5];
  const float* W2   = (const float*)d_in[6];
  const float* b2   = (const float*)d_in[7];
  float* out = (float*)d_out;
  float* wsf = (float*)d_ws;
  float* mu     = wsf;
  float* rstd   = wsf + BTc;
  float* scores = wsf + 2 * BTc;
  ushort* w1s   = (ushort*)(wsf + 3 * BTc);  // 3 planes * 1.5 MB

  w1_split_k<<<384, 256, 0, stream>>>(W1, w1s);
  ln_stats_k<<<BTc / 4, 256, 0, stream>>>(emb, attn, mu, rstd);
  gemm_scores_mfma2<<<BTc / 64, 512, 0, stream>>>(
      emb, attn, ln_g, ln_b, w1s, b1, W2, b2, mu, rstd, scores);
  entmax_rank_k<<<Bc, 256, 0, stream>>>(scores, attn, out);
}

// Round 5
// 1454.326 us; speedup vs baseline: 1.7589x; 1.0612x over previous
//
#include <hip/hip_runtime.h>
#include <math.h>

#define Bc 32
#define Tc 4096
#define Dc 768
#define Hc 1024
#define BTc (Bc*Tc)
#define PLANE 786432   // 96*1024*8 ushorts per split plane

typedef __bf16 bf16x8 __attribute__((ext_vector_type(8)));
typedef float f32x16 __attribute__((ext_vector_type(16)));

__device__ __forceinline__ float gelu_erf(float x) {
  return 0.5f * x * (1.0f + erff(x * 0.70710678118654752440f));
}
__device__ __forceinline__ unsigned bf16rne(float x) {
  unsigned u = __float_as_uint(x);
  return (u + 0x7FFFu + ((u >> 16) & 1u)) >> 16;
}
// exact 3-way bf16 split: x ~= hi+mid+lo, residual ~2^-27 |x|
__device__ __forceinline__ void split3(float x, unsigned& h, unsigned& m, unsigned& l) {
  h = bf16rne(x);
  float r1 = x - __uint_as_float(h << 16);
  m = bf16rne(r1);
  float r2 = r1 - __uint_as_float(m << 16);
  l = bf16rne(r2);
}
__device__ __forceinline__ unsigned f2o(float f) {
  unsigned b = __float_as_uint(f);
  return (b & 0x80000000u) ? ~b : (b | 0x80000000u);
}
__device__ __forceinline__ float o2f(unsigned o) {
  unsigned b = (o & 0x80000000u) ? (o & 0x7FFFFFFFu) : ~o;
  return __uint_as_float(b);
}

// ---------------- Kernel 0: pre-split W1 into 3 bf16 planes -----------------
// layout: w1s[s*PLANE + (kg*1024 + n)*8 + j]  for element (k=kg*8+j, n)
__global__ __launch_bounds__(256) void w1_split_k(
    const float* __restrict__ W1, ushort* __restrict__ w1s) {
  int id = blockIdx.x * 256 + threadIdx.x;   // 96*1024 total
  int n = id & 1023, kg = id >> 10;
  unsigned hs[8], ms[8], ls[8];
  #pragma unroll
  for (int j = 0; j < 8; j++) {
    float x = W1[(size_t)(kg * 8 + j) * Hc + n];
    split3(x, hs[j], ms[j], ls[j]);
  }
  size_t o = ((size_t)kg * 1024 + n) * 8;
  int4 ph, pm, pl;
  ph.x = (int)(hs[0] | (hs[1] << 16)); ph.y = (int)(hs[2] | (hs[3] << 16));
  ph.z = (int)(hs[4] | (hs[5] << 16)); ph.w = (int)(hs[6] | (hs[7] << 16));
  pm.x = (int)(ms[0] | (ms[1] << 16)); pm.y = (int)(ms[2] | (ms[3] << 16));
  pm.z = (int)(ms[4] | (ms[5] << 16)); pm.w = (int)(ms[6] | (ms[7] << 16));
  pl.x = (int)(ls[0] | (ls[1] << 16)); pl.y = (int)(ls[2] | (ls[3] << 16));
  pl.z = (int)(ls[4] | (ls[5] << 16)); pl.w = (int)(ls[6] | (ls[7] << 16));
  *(int4*)(w1s + o)             = ph;
  *(int4*)(w1s + o + PLANE)     = pm;
  *(int4*)(w1s + o + 2 * PLANE) = pl;
}

// ---------------- Kernel 1: masked LayerNorm stats (mu, rstd per row) -------
__global__ __launch_bounds__(256) void ln_stats_k(
    const float* __restrict__ emb, const float* __restrict__ attn,
    float* __restrict__ mu, float* __restrict__ rstd) {
  int row = blockIdx.x * 4 + (threadIdx.x >> 6);
  int lane = threadIdx.x & 63;
  float a = attn[row];
  const float4* e = (const float4*)(emb + (size_t)row * Dc);
  float4 v0 = e[lane], v1 = e[lane + 64], v2 = e[lane + 128];
  float x[12] = {v0.x*a, v0.y*a, v0.z*a, v0.w*a,
                 v1.x*a, v1.y*a, v1.z*a, v1.w*a,
                 v2.x*a, v2.y*a, v2.z*a, v2.w*a};
  float s = 0.f;
  #pragma unroll
  for (int i = 0; i < 12; i++) s += x[i];
  #pragma unroll
  for (int o = 32; o; o >>= 1) s += __shfl_xor(s, o);
  float m = s / 768.0f;
  float q = 0.f;
  #pragma unroll
  for (int i = 0; i < 12; i++) { float d = x[i] - m; q += d * d; }
  #pragma unroll
  for (int o = 32; o; o >>= 1) q += __shfl_xor(q, o);
  float var = q / 768.0f;
  if (lane == 0) { mu[row] = m; rstd[row] = 1.0f / sqrtf(var + 1e-5f); }
}

// ---- Kernel 2: MFMA GEMM, H split across blockIdx.y (2 halves of 512). ----
// Block: 64 rows x 512 cols, 8 waves (2M x 4N), wave = 32 rows x 128 cols ->
// acc[4] = 64 VGPR (fits: NO spill). B frags straight from pre-split W1
// planes (L2/L3). A: LN+split3, all 512 threads stage 4 k-elems each with
// consecutive-8B LDS writes (conflict-free), double-buffered.
__global__ __launch_bounds__(512, 2) void gemm_scores_mfma3(
    const float* __restrict__ emb, const float* __restrict__ attn,
    const float* __restrict__ ln_g, const float* __restrict__ ln_b,
    const ushort* __restrict__ w1s, const float* __restrict__ b1,
    const float* __restrict__ W2, const float* __restrict__ b2,
    const float* __restrict__ mu, const float* __restrict__ rstd,
    float* __restrict__ spart) {
  __shared__ int4 Abuf[2][3][4][64];   // 24 KB: [buf][split][kg][row] 16B
  __shared__ float gls[768], bls[768]; // 6 KB
  __shared__ float red[4][64];         // 1 KB
  const int base = blockIdx.x * 64;
  if (attn[base] == 0.0f) return;      // attn is a prefix mask
  const int hbase = blockIdx.y * 512;
  const int t = threadIdx.x;
  const int lane = t & 63;
  const int lrow = lane & 31;
  const int lkg = lane >> 5;
  const int w = t >> 6, wm = w >> 2, wn = w & 3;

  if (t < 192) {
    *(float4*)&gls[t * 4] = *(const float4*)&ln_g[t * 4];
    *(float4*)&bls[t * 4] = *(const float4*)&ln_b[t * 4];
  }
  // staging identity: all 512 threads, 4 k-elems each; lane->consecutive 8B
  const int sub = t & 1;
  const int srow = (t >> 1) & 63;
  const int skg = t >> 7;              // 0..3
  const int skoff = skg * 8 + sub * 4;
  const float la  = attn[base + srow];
  const float lmu = mu[base + srow];
  const float lrs = rstd[base + srow];
  const float* erow = emb + (size_t)(base + srow) * Dc + skoff;

  f32x16 acc[4];
  #pragma unroll
  for (int nt = 0; nt < 4; nt++)
    #pragma unroll
    for (int r = 0; r < 16; r++) acc[nt][r] = 0.f;

  __syncthreads();  // gls/bls visible
  // ---- prologue: stage k0=0 into buf 0 ----
  {
    float4 ev = *(const float4*)(erow);
    float4 gv = *(const float4*)&gls[skoff];
    float4 bv = *(const float4*)&bls[skoff];
    float xs[4] = {ev.x, ev.y, ev.z, ev.w};
    float gs[4] = {gv.x, gv.y, gv.z, gv.w};
    float bs[4] = {bv.x, bv.y, bv.z, bv.w};
    unsigned hh[4], hm[4], hl[4];
    #pragma unroll
    for (int e = 0; e < 4; e++) {
      float xn = (xs[e] * la - lmu) * lrs * gs[e] + bs[e];
      split3(xn, hh[e], hm[e], hl[e]);
    }
    char* bw = (char*)&Abuf[0][0][skg][srow] + sub * 8;
    *(int2*)bw          = make_int2((int)(hh[0] | (hh[1] << 16)), (int)(hh[2] | (hh[3] << 16)));
    *(int2*)(bw + 4096) = make_int2((int)(hm[0] | (hm[1] << 16)), (int)(hm[2] | (hm[3] << 16)));
    *(int2*)(bw + 8192) = make_int2((int)(hl[0] | (hl[1] << 16)), (int)(hl[2] | (hl[3] << 16)));
  }
  __syncthreads();

  #pragma unroll 1
  for (int i = 0; i < 24; i++) {
    const int p = i & 1;
    const bool more = (i < 23);
    float4 evn;
    if (more) evn = *(const float4*)(erow + (i + 1) * 32);  // early issue
    #pragma unroll 1
    for (int kh = 0; kh < 2; kh++) {
      bf16x8 af0 = *(const bf16x8*)&Abuf[p][0][kh * 2 + lkg][wm * 32 + lrow];
      bf16x8 af1 = *(const bf16x8*)&Abuf[p][1][kh * 2 + lkg][wm * 32 + lrow];
      bf16x8 af2 = *(const bf16x8*)&Abuf[p][2][kh * 2 + lkg][wm * 32 + lrow];
      const size_t kgg = (size_t)(i * 4 + kh * 2 + lkg);
      const ushort* bp0 = w1s + (kgg * 1024 + hbase + wn * 128 + lrow) * 8;
      #pragma unroll
      for (int nt = 0; nt < 4; nt++) {
        const ushort* bp = bp0 + nt * 256;   // 32 cols * 8
        bf16x8 bh = *(const bf16x8*)(bp);
        bf16x8 bm = *(const bf16x8*)(bp + PLANE);
        bf16x8 bl = *(const bf16x8*)(bp + 2 * PLANE);
        acc[nt] = __builtin_amdgcn_mfma_f32_32x32x16_bf16(af0, bh, acc[nt], 0, 0, 0);
        acc[nt] = __builtin_amdgcn_mfma_f32_32x32x16_bf16(af0, bm, acc[nt], 0, 0, 0);
        acc[nt] = __builtin_amdgcn_mfma_f32_32x32x16_bf16(af1, bh, acc[nt], 0, 0, 0);
        acc[nt] = __builtin_amdgcn_mfma_f32_32x32x16_bf16(af1, bm, acc[nt], 0, 0, 0);
        acc[nt] = __builtin_amdgcn_mfma_f32_32x32x16_bf16(af0, bl, acc[nt], 0, 0, 0);
        acc[nt] = __builtin_amdgcn_mfma_f32_32x32x16_bf16(af2, bh, acc[nt], 0, 0, 0);
      }
    }
    if (more) {
      const int koff = (i + 1) * 32 + skoff;
      float4 gv = *(const float4*)&gls[koff];
      float4 bv = *(const float4*)&bls[koff];
      float xs[4] = {evn.x, evn.y, evn.z, evn.w};
      float gs[4] = {gv.x, gv.y, gv.z, gv.w};
      float bs[4] = {bv.x, bv.y, bv.z, bv.w};
      unsigned hh[4], hm[4], hl[4];
      #pragma unroll
      for (int e = 0; e < 4; e++) {
        float xn = (xs[e] * la - lmu) * lrs * gs[e] + bs[e];
        split3(xn, hh[e], hm[e], hl[e]);
      }
      char* bw = (char*)&Abuf[p ^ 1][0][skg][srow] + sub * 8;
      *(int2*)bw          = make_int2((int)(hh[0] | (hh[1] << 16)), (int)(hh[2] | (hh[3] << 16)));
      *(int2*)(bw + 4096) = make_int2((int)(hm[0] | (hm[1] << 16)), (int)(hm[2] | (hm[3] << 16)));
      *(int2*)(bw + 8192) = make_int2((int)(hl[0] | (hl[1] << 16)), (int)(hl[2] | (hl[3] << 16)));
    }
    __syncthreads();
  }

  // ---- epilogue: bias + erf-gelu + W2 dot (this half), partial reduce ----
  float sacc[16];
  #pragma unroll
  for (int r = 0; r < 16; r++) sacc[r] = 0.f;
  #pragma unroll
  for (int nt = 0; nt < 4; nt++) {
    const int col = hbase + wn * 128 + nt * 32 + lrow;
    const float b1v = b1[col];
    const float w2v = W2[col];
    #pragma unroll
    for (int r = 0; r < 16; r++)
      sacc[r] += gelu_erf(acc[nt][r] + b1v) * w2v;
  }
  #pragma unroll
  for (int r = 0; r < 16; r++) {
    float v = sacc[r];
    v += __shfl_xor(v, 1);  v += __shfl_xor(v, 2);  v += __shfl_xor(v, 4);
    v += __shfl_xor(v, 8);  v += __shfl_xor(v, 16);
    if (lrow == 0) {
      int row = wm * 32 + (r & 3) + 8 * (r >> 2) + 4 * lkg;
      red[wn][row] = v;
    }
  }
  __syncthreads();
  if (t < 64) {
    float v = red[0][t] + red[1][t] + red[2][t] + red[3][t];
    if (blockIdx.y == 0) v += b2[0];
    spart[blockIdx.y * BTc + base + t] = v;
  }
}

// ---- Kernel 3: 1.5-entmax (f64 tau), exact stable ranking, h-mask writes ---
__global__ __launch_bounds__(256) void entmax_rank_k(
    const float* __restrict__ sp0, const float* __restrict__ sp1,
    const float* __restrict__ attn, float* __restrict__ out) {
  const int N = 4096;
  __shared__ unsigned long long keys[4096];
  __shared__ double tsum[256], tsq[256];
  __shared__ int tcnt[256];
  __shared__ float sred[4];
  __shared__ double sh_tau;
  __shared__ int sh_S, sh_m, sh_k[5];
  const int b = blockIdx.x;
  const int t = threadIdx.x;
  const float* srow0 = sp0 + b * N;
  const float* srow1 = sp1 + b * N;
  const float* arow = attn + b * N;
  float teff_l = 0.f;
  for (int i = t; i < N; i += 256) {
    float a = arow[i];
    float s = srow0[i] + srow1[i];
    float xe = (a == 0.f) ? -1e9f : s;
    teff_l += a;
    keys[i] = ((unsigned long long)f2o(xe) << 32) |
              (unsigned long long)(0xFFFFFFFFu - (unsigned)i);
  }
  #pragma unroll
  for (int o = 32; o; o >>= 1) teff_l += __shfl_xor(teff_l, o);
  if ((t & 63) == 0) sred[t >> 6] = teff_l;
  __syncthreads();
  if (t == 0) {
    float te = sred[0] + sred[1] + sred[2] + sred[3];
    const float rh[5] = {0.1f, 0.3f, 0.5f, 0.7f, 0.9f};
    for (int r = 0; r < 5; r++) {
      int ki = (int)floorf(rh[r] * te);   // must be f32 math
      sh_k[r] = ki < 1 ? 1 : ki;
    }
  }
  for (int kk = 2; kk <= N; kk <<= 1) {
    for (int j = kk >> 1; j > 0; j >>= 1) {
      __syncthreads();
      for (int idx = t; idx < N / 2; idx += 256) {
        int i = 2 * idx - (idx & (j - 1));
        int l = i | j;
        unsigned long long A = keys[i], Bv = keys[l];
        bool up = ((i & kk) == 0);
        if (up ? (A < Bv) : (A > Bv)) { keys[i] = Bv; keys[l] = A; }
      }
    }
  }
  __syncthreads();
  const int base = t * 16;
  {
    double ls = 0, lq = 0;
    for (int ii = 0; ii < 16; ii++) {
      double x = 0.5 * (double)o2f((unsigned)(keys[base + ii] >> 32));
      ls += x; lq += x * x;
    }
    tsum[t] = ls; tsq[t] = lq;
  }
  __syncthreads();
  if (t == 0) {
    double rs = 0, rq = 0;
    for (int i = 0; i < 256; i++) {
      double a = tsum[i], c = tsq[i];
      tsum[i] = rs; tsq[i] = rq; rs += a; rq += c;
    }
  }
  __syncthreads();
  {
    double cs = tsum[t], cq = tsq[t];
    int lc = 0;
    for (int ii = 0; ii < 16; ii++) {
      double x = 0.5 * (double)o2f((unsigned)(keys[base + ii] >> 32));
      cs += x; cq += x * x;
      double rho = (double)(base + ii + 1);
      double mean = cs / rho, msq = cq / rho;
      double ss = rho * (msq - mean * mean);
      double delta = (1.0 - ss) / rho;
      double dl = delta > 0.0 ? delta : 0.0;
      double tau = mean - sqrt(dl);
      if (tau <= x) lc++;
    }
    tcnt[t] = lc;
  }
  __syncthreads();
  if (t == 0) {
    int r = 0;
    for (int i = 0; i < 256; i++) { int c = tcnt[i]; tcnt[i] = r; r += c; }
    sh_S = r;
  }
  __syncthreads();
  {
    int jstar = sh_S - 1;
    if (jstar >= base && jstar < base + 16) {
      double cs = tsum[t], cq = tsq[t], tau = 0.0;
      for (int ii = 0; ii <= jstar - base; ii++) {
        double x = 0.5 * (double)o2f((unsigned)(keys[base + ii] >> 32));
        cs += x; cq += x * x;
        double rho = (double)(base + ii + 1);
        double mean = cs / rho, msq = cq / rho;
        double ss = rho * (msq - mean * mean);
        double delta = (1.0 - ss) / rho;
        double dl = delta > 0.0 ? delta : 0.0;
        tau = mean - sqrt(dl);
      }
      sh_tau = tau;
    }
  }
  __syncthreads();
  const double tau = sh_tau;
  float ps[16], pa[16];
  {
    int lf = 0;
    for (int ii = 0; ii < 16; ii++) {
      int p = base + ii;
      ps[ii] = srow0[p] + srow1[p]; pa[ii] = arow[p];
      double d = 0.5 * (double)ps[ii] - tau;
      if (pa[ii] != 0.f && d > 0.0) lf++;
    }
    tcnt[t] = lf;
  }
  __syncthreads();
  if (t == 0) {
    int r = 0;
    for (int i = 0; i < 256; i++) { int c = tcnt[i]; tcnt[i] = r; r += c; }
    sh_m = r;
  }
  __syncthreads();
  const int m = sh_m;
  const int k0_ = sh_k[0], k1_ = sh_k[1], k2_ = sh_k[2], k3_ = sh_k[3], k4_ = sh_k[4];
  {
    int cex = tcnt[t];
    for (int ii = 0; ii < 16; ii++) {
      int p = base + ii;
      double d = 0.5 * (double)ps[ii] - tau;
      bool av = (pa[ii] != 0.f);
      bool sup = av && (d > 0.0);
      out[b * N + p] = sup ? (float)(d * d) : 0.0f;
      if (!sup) {
        int rank = m + p - cex;
        out[1 * BTc + b * N + p] = (av && rank < k0_) ? 1.f : 0.f;
        out[2 * BTc + b * N + p] = (av && rank < k1_) ? 1.f : 0.f;
        out[3 * BTc + b * N + p] = (av && rank < k2_) ? 1.f : 0.f;
        out[4 * BTc + b * N + p] = (av && rank < k3_) ? 1.f : 0.f;
        out[5 * BTc + b * N + p] = (av && rank < k4_) ? 1.f : 0.f;
      } else {
        cex++;
      }
    }
  }
  for (int r = t; r < m; r += 256) {
    int i = (int)(0xFFFFFFFFu - (unsigned)(keys[r] & 0xFFFFFFFFull));
    out[1 * BTc + b * N + i] = (r < k0_) ? 1.f : 0.f;
    out[2 * BTc + b * N + i] = (r < k1_) ? 1.f : 0.f;
    out[3 * BTc + b * N + i] = (r < k2_) ? 1.f : 0.f;
    out[4 * BTc + b * N + i] = (r < k3_) ? 1.f : 0.f;
    out[5 * BTc + b * N + i] = (r < k4_) ? 1.f : 0.f;
  }
}

extern "C" void kernel_launch(void* const* d_in, const int* in_sizes, int n_in,
                              void* d_out, int out_size, void* d_ws, size_t ws_size,
                              hipStream_t stream) {
  (void)in_sizes; (void)n_in; (void)out_size; (void)ws_size;
  const float* emb  = (const float*)d_in[0];
  const float* attn = (const float*)d_in[1];
  const float* ln_g = (const float*)d_in[2];
  const float* ln_b = (const float*)d_in[3];
  const float* W1   = (const float*)d_in[4];
  const float* b1   = (const float*)d_in[5];
  const float* W2   = (const float*)d_in[6];
  const float* b2   = (const float*)d_in[7];
  float* out = (float*)d_out;
  float* wsf = (float*)d_ws;
  float* mu     = wsf;
  float* rstd   = wsf + BTc;
  float* spart  = wsf + 2 * BTc;             // [2][BTc]
  ushort* w1s   = (ushort*)(wsf + 4 * BTc);  // 3 planes * 1.5 MB

  w1_split_k<<<384, 256, 0, stream>>>(W1, w1s);
  ln_stats_k<<<BTc / 4, 256, 0, stream>>>(emb, attn, mu, rstd);
  gemm_scores_mfma3<<<dim3(BTc / 64, 2), 512, 0, stream>>>(
      emb, attn, ln_g, ln_b, w1s, b1, W2, b2, mu, rstd, spart);
  entmax_rank_k<<<Bc, 256, 0, stream>>>(spart, spart + BTc, attn, out);
}

// Round 6
// 1320.182 us; speedup vs baseline: 1.9377x; 1.1016x over previous
//
#include <hip/hip_runtime.h>
#include <math.h>

#define Bc 32
#define Tc 4096
#define Dc 768
#define Hc 1024
#define BTc (Bc*Tc)
#define PLANE 786432   // 96*1024*8 ushorts per split plane

typedef __bf16 bf16x8 __attribute__((ext_vector_type(8)));
typedef float f32x16 __attribute__((ext_vector_type(16)));

__device__ __forceinline__ float gelu_erf(float x) {
  return 0.5f * x * (1.0f + erff(x * 0.70710678118654752440f));
}
__device__ __forceinline__ unsigned bf16rne(float x) {
  unsigned u = __float_as_uint(x);
  return (u + 0x7FFFu + ((u >> 16) & 1u)) >> 16;
}
// exact 3-way bf16 split: x ~= hi+mid+lo, residual ~2^-27 |x|
__device__ __forceinline__ void split3(float x, unsigned& h, unsigned& m, unsigned& l) {
  h = bf16rne(x);
  float r1 = x - __uint_as_float(h << 16);
  m = bf16rne(r1);
  float r2 = r1 - __uint_as_float(m << 16);
  l = bf16rne(r2);
}
__device__ __forceinline__ unsigned f2o(float f) {
  unsigned b = __float_as_uint(f);
  return (b & 0x80000000u) ? ~b : (b | 0x80000000u);
}
__device__ __forceinline__ float o2f(unsigned o) {
  unsigned b = (o & 0x80000000u) ? (o & 0x7FFFFFFFu) : ~o;
  return __uint_as_float(b);
}

// B-fragment register block: one kh-phase (12 x 16B = 48 VGPRs)
struct Bfrag { bf16x8 h[4], m[4], l[4]; };

__device__ __forceinline__ void loadB(const ushort* __restrict__ bp0, Bfrag& B) {
  #pragma unroll
  for (int nt = 0; nt < 4; nt++) {
    const ushort* bp = bp0 + nt * 256;     // 32 cols * 8
    B.h[nt] = *(const bf16x8*)(bp);
    B.m[nt] = *(const bf16x8*)(bp + PLANE);
    B.l[nt] = *(const bf16x8*)(bp + 2 * PLANE);
  }
}

__device__ __forceinline__ void mfma6(bf16x8 a0, bf16x8 a1, bf16x8 a2,
                                      const Bfrag& B, f32x16* acc) {
  #pragma unroll
  for (int nt = 0; nt < 4; nt++) {   // order identical to prior rounds
    acc[nt] = __builtin_amdgcn_mfma_f32_32x32x16_bf16(a0, B.h[nt], acc[nt], 0, 0, 0);
    acc[nt] = __builtin_amdgcn_mfma_f32_32x32x16_bf16(a0, B.m[nt], acc[nt], 0, 0, 0);
    acc[nt] = __builtin_amdgcn_mfma_f32_32x32x16_bf16(a1, B.h[nt], acc[nt], 0, 0, 0);
    acc[nt] = __builtin_amdgcn_mfma_f32_32x32x16_bf16(a1, B.m[nt], acc[nt], 0, 0, 0);
    acc[nt] = __builtin_amdgcn_mfma_f32_32x32x16_bf16(a0, B.l[nt], acc[nt], 0, 0, 0);
    acc[nt] = __builtin_amdgcn_mfma_f32_32x32x16_bf16(a2, B.h[nt], acc[nt], 0, 0, 0);
  }
}

// ---------------- Kernel 0: pre-split W1 into 3 bf16 planes -----------------
__global__ __launch_bounds__(256) void w1_split_k(
    const float* __restrict__ W1, ushort* __restrict__ w1s) {
  int id = blockIdx.x * 256 + threadIdx.x;   // 96*1024 total
  int n = id & 1023, kg = id >> 10;
  unsigned hs[8], ms[8], ls[8];
  #pragma unroll
  for (int j = 0; j < 8; j++) {
    float x = W1[(size_t)(kg * 8 + j) * Hc + n];
    split3(x, hs[j], ms[j], ls[j]);
  }
  size_t o = ((size_t)kg * 1024 + n) * 8;
  int4 ph, pm, pl;
  ph.x = (int)(hs[0] | (hs[1] << 16)); ph.y = (int)(hs[2] | (hs[3] << 16));
  ph.z = (int)(hs[4] | (hs[5] << 16)); ph.w = (int)(hs[6] | (hs[7] << 16));
  pm.x = (int)(ms[0] | (ms[1] << 16)); pm.y = (int)(ms[2] | (ms[3] << 16));
  pm.z = (int)(ms[4] | (ms[5] << 16)); pm.w = (int)(ms[6] | (ms[7] << 16));
  pl.x = (int)(ls[0] | (ls[1] << 16)); pl.y = (int)(ls[2] | (ls[3] << 16));
  pl.z = (int)(ls[4] | (ls[5] << 16)); pl.w = (int)(ls[6] | (ls[7] << 16));
  *(int4*)(w1s + o)             = ph;
  *(int4*)(w1s + o + PLANE)     = pm;
  *(int4*)(w1s + o + 2 * PLANE) = pl;
}

// ---------------- Kernel 1: masked LayerNorm stats (mu, rstd per row) -------
__global__ __launch_bounds__(256) void ln_stats_k(
    const float* __restrict__ emb, const float* __restrict__ attn,
    float* __restrict__ mu, float* __restrict__ rstd) {
  int row = blockIdx.x * 4 + (threadIdx.x >> 6);
  int lane = threadIdx.x & 63;
  float a = attn[row];
  const float4* e = (const float4*)(emb + (size_t)row * Dc);
  float4 v0 = e[lane], v1 = e[lane + 64], v2 = e[lane + 128];
  float x[12] = {v0.x*a, v0.y*a, v0.z*a, v0.w*a,
                 v1.x*a, v1.y*a, v1.z*a, v1.w*a,
                 v2.x*a, v2.y*a, v2.z*a, v2.w*a};
  float s = 0.f;
  #pragma unroll
  for (int i = 0; i < 12; i++) s += x[i];
  #pragma unroll
  for (int o = 32; o; o >>= 1) s += __shfl_xor(s, o);
  float m = s / 768.0f;
  float q = 0.f;
  #pragma unroll
  for (int i = 0; i < 12; i++) { float d = x[i] - m; q += d * d; }
  #pragma unroll
  for (int o = 32; o; o >>= 1) q += __shfl_xor(q, o);
  float var = q / 768.0f;
  if (lane == 0) { mu[row] = m; rstd[row] = 1.0f / sqrtf(var + 1e-5f); }
}

// ---- Kernel 2: MFMA GEMM with register-pipelined B. H split over y (2). ----
// Block 64 rows x 512 cols, 8 waves (2M x 4N), wave 32x128 -> acc[4]=64 VGPR.
// B: two Bfrag register blocks (96 VGPR) rotate so every load phase is
// covered by a compute phase. 256-reg budget: launch_bounds(512,1).
__global__ __launch_bounds__(512, 1) void gemm_scores_mfma4(
    const float* __restrict__ emb, const float* __restrict__ attn,
    const float* __restrict__ ln_g, const float* __restrict__ ln_b,
    const ushort* __restrict__ w1s, const float* __restrict__ b1,
    const float* __restrict__ W2, const float* __restrict__ b2,
    const float* __restrict__ mu, const float* __restrict__ rstd,
    float* __restrict__ spart) {
  __shared__ int4 Abuf[2][3][4][64];   // 24 KB: [buf][split][kg][row] 16B
  __shared__ float gls[768], bls[768]; // 6 KB
  __shared__ float red[4][64];         // 1 KB
  const int base = blockIdx.x * 64;
  if (attn[base] == 0.0f) return;      // attn is a prefix mask
  const int hbase = blockIdx.y * 512;
  const int t = threadIdx.x;
  const int lane = t & 63;
  const int lrow = lane & 31;
  const int lkg = lane >> 5;
  const int w = t >> 6, wm = w >> 2, wn = w & 3;

  if (t < 192) {
    *(float4*)&gls[t * 4] = *(const float4*)&ln_g[t * 4];
    *(float4*)&bls[t * 4] = *(const float4*)&ln_b[t * 4];
  }
  // staging identity: all 512 threads, 4 k-elems each; lane->consecutive 8B
  const int sub = t & 1;
  const int srow = (t >> 1) & 63;
  const int skg = t >> 7;              // 0..3
  const int skoff = skg * 8 + sub * 4;
  const float la  = attn[base + srow];
  const float lmu = mu[base + srow];
  const float lrs = rstd[base + srow];
  const float* erow = emb + (size_t)(base + srow) * Dc + skoff;

  f32x16 acc[4];
  #pragma unroll
  for (int nt = 0; nt < 4; nt++)
    #pragma unroll
    for (int r = 0; r < 16; r++) acc[nt][r] = 0.f;

  __syncthreads();  // gls/bls visible
  // ---- prologue: stage k0=0 into buf 0 ----
  {
    float4 ev = *(const float4*)(erow);
    float4 gv = *(const float4*)&gls[skoff];
    float4 bv = *(const float4*)&bls[skoff];
    float xs[4] = {ev.x, ev.y, ev.z, ev.w};
    float gs[4] = {gv.x, gv.y, gv.z, gv.w};
    float bs[4] = {bv.x, bv.y, bv.z, bv.w};
    unsigned hh[4], hm[4], hl[4];
    #pragma unroll
    for (int e = 0; e < 4; e++) {
      float xn = (xs[e] * la - lmu) * lrs * gs[e] + bs[e];
      split3(xn, hh[e], hm[e], hl[e]);
    }
    char* bw = (char*)&Abuf[0][0][skg][srow] + sub * 8;
    *(int2*)bw          = make_int2((int)(hh[0] | (hh[1] << 16)), (int)(hh[2] | (hh[3] << 16)));
    *(int2*)(bw + 4096) = make_int2((int)(hm[0] | (hm[1] << 16)), (int)(hm[2] | (hm[3] << 16)));
    *(int2*)(bw + 8192) = make_int2((int)(hl[0] | (hl[1] << 16)), (int)(hl[2] | (hl[3] << 16)));
  }
  __syncthreads();

  // per-lane B base: addr(i,kh) = wbase + (i*4 + kh*2 + lkg)*8192
  const ushort* wbase = w1s + ((size_t)hbase + wn * 128 + lrow) * 8;

  Bfrag Ba, Bb;
  loadB(wbase + (size_t)lkg * 8192, Ba);   // (i=0, kh=0)

  #pragma unroll 1
  for (int i = 0; i < 24; i++) {
    const int p = i & 1;
    const bool more = (i < 23);
    float4 evn;
    if (more) evn = *(const float4*)(erow + (i + 1) * 32);   // A prefetch
    loadB(wbase + (size_t)(i * 4 + 2 + lkg) * 8192, Bb);     // kh=1 prefetch
    {
      bf16x8 a0 = *(const bf16x8*)&Abuf[p][0][lkg][wm * 32 + lrow];
      bf16x8 a1 = *(const bf16x8*)&Abuf[p][1][lkg][wm * 32 + lrow];
      bf16x8 a2 = *(const bf16x8*)&Abuf[p][2][lkg][wm * 32 + lrow];
      mfma6(a0, a1, a2, Ba, acc);                            // kh=0
    }
    if (more) loadB(wbase + (size_t)((i + 1) * 4 + lkg) * 8192, Ba);  // next kh=0
    {
      bf16x8 a0 = *(const bf16x8*)&Abuf[p][0][2 + lkg][wm * 32 + lrow];
      bf16x8 a1 = *(const bf16x8*)&Abuf[p][1][2 + lkg][wm * 32 + lrow];
      bf16x8 a2 = *(const bf16x8*)&Abuf[p][2][2 + lkg][wm * 32 + lrow];
      mfma6(a0, a1, a2, Bb, acc);                            // kh=1
    }
    if (more) {
      const int koff = (i + 1) * 32 + skoff;
      float4 gv = *(const float4*)&gls[koff];
      float4 bv = *(const float4*)&bls[koff];
      float xs[4] = {evn.x, evn.y, evn.z, evn.w};
      float gs[4] = {gv.x, gv.y, gv.z, gv.w};
      float bs[4] = {bv.x, bv.y, bv.z, bv.w};
      unsigned hh[4], hm[4], hl[4];
      #pragma unroll
      for (int e = 0; e < 4; e++) {
        float xn = (xs[e] * la - lmu) * lrs * gs[e] + bs[e];
        split3(xn, hh[e], hm[e], hl[e]);
      }
      char* bw = (char*)&Abuf[p ^ 1][0][skg][srow] + sub * 8;
      *(int2*)bw          = make_int2((int)(hh[0] | (hh[1] << 16)), (int)(hh[2] | (hh[3] << 16)));
      *(int2*)(bw + 4096) = make_int2((int)(hm[0] | (hm[1] << 16)), (int)(hm[2] | (hm[3] << 16)));
      *(int2*)(bw + 8192) = make_int2((int)(hl[0] | (hl[1] << 16)), (int)(hl[2] | (hl[3] << 16)));
    }
    __syncthreads();
  }

  // ---- epilogue: bias + erf-gelu + W2 dot (this half), partial reduce ----
  float sacc[16];
  #pragma unroll
  for (int r = 0; r < 16; r++) sacc[r] = 0.f;
  #pragma unroll
  for (int nt = 0; nt < 4; nt++) {
    const int col = hbase + wn * 128 + nt * 32 + lrow;
    const float b1v = b1[col];
    const float w2v = W2[col];
    #pragma unroll
    for (int r = 0; r < 16; r++)
      sacc[r] += gelu_erf(acc[nt][r] + b1v) * w2v;
  }
  #pragma unroll
  for (int r = 0; r < 16; r++) {
    float v = sacc[r];
    v += __shfl_xor(v, 1);  v += __shfl_xor(v, 2);  v += __shfl_xor(v, 4);
    v += __shfl_xor(v, 8);  v += __shfl_xor(v, 16);
    if (lrow == 0) {
      int row = wm * 32 + (r & 3) + 8 * (r >> 2) + 4 * lkg;
      red[wn][row] = v;
    }
  }
  __syncthreads();
  if (t < 64) {
    float v = red[0][t] + red[1][t] + red[2][t] + red[3][t];
    if (blockIdx.y == 0) v += b2[0];
    spart[blockIdx.y * BTc + base + t] = v;
  }
}

// ---- Kernel 3: 1.5-entmax (f64 tau), exact stable ranking, h-mask writes ---
__global__ __launch_bounds__(256) void entmax_rank_k(
    const float* __restrict__ sp0, const float* __restrict__ sp1,
    const float* __restrict__ attn, float* __restrict__ out) {
  const int N = 4096;
  __shared__ unsigned long long keys[4096];
  __shared__ double tsum[256], tsq[256];
  __shared__ int tcnt[256];
  __shared__ float sred[4];
  __shared__ double sh_tau;
  __shared__ int sh_S, sh_m, sh_k[5];
  const int b = blockIdx.x;
  const int t = threadIdx.x;
  const float* srow0 = sp0 + b * N;
  const float* srow1 = sp1 + b * N;
  const float* arow = attn + b * N;
  float teff_l = 0.f;
  for (int i = t; i < N; i += 256) {
    float a = arow[i];
    float s = srow0[i] + srow1[i];
    float xe = (a == 0.f) ? -1e9f : s;
    teff_l += a;
    keys[i] = ((unsigned long long)f2o(xe) << 32) |
              (unsigned long long)(0xFFFFFFFFu - (unsigned)i);
  }
  #pragma unroll
  for (int o = 32; o; o >>= 1) teff_l += __shfl_xor(teff_l, o);
  if ((t & 63) == 0) sred[t >> 6] = teff_l;
  __syncthreads();
  if (t == 0) {
    float te = sred[0] + sred[1] + sred[2] + sred[3];
    const float rh[5] = {0.1f, 0.3f, 0.5f, 0.7f, 0.9f};
    for (int r = 0; r < 5; r++) {
      int ki = (int)floorf(rh[r] * te);   // must be f32 math
      sh_k[r] = ki < 1 ? 1 : ki;
    }
  }
  for (int kk = 2; kk <= N; kk <<= 1) {
    for (int j = kk >> 1; j > 0; j >>= 1) {
      __syncthreads();
      for (int idx = t; idx < N / 2; idx += 256) {
        int i = 2 * idx - (idx & (j - 1));
        int l = i | j;
        unsigned long long A = keys[i], Bv = keys[l];
        bool up = ((i & kk) == 0);
        if (up ? (A < Bv) : (A > Bv)) { keys[i] = Bv; keys[l] = A; }
      }
    }
  }
  __syncthreads();
  const int base = t * 16;
  {
    double ls = 0, lq = 0;
    for (int ii = 0; ii < 16; ii++) {
      double x = 0.5 * (double)o2f((unsigned)(keys[base + ii] >> 32));
      ls += x; lq += x * x;
    }
    tsum[t] = ls; tsq[t] = lq;
  }
  __syncthreads();
  if (t == 0) {
    double rs = 0, rq = 0;
    for (int i = 0; i < 256; i++) {
      double a = tsum[i], c = tsq[i];
      tsum[i] = rs; tsq[i] = rq; rs += a; rq += c;
    }
  }
  __syncthreads();
  {
    double cs = tsum[t], cq = tsq[t];
    int lc = 0;
    for (int ii = 0; ii < 16; ii++) {
      double x = 0.5 * (double)o2f((unsigned)(keys[base + ii] >> 32));
      cs += x; cq += x * x;
      double rho = (double)(base + ii + 1);
      double mean = cs / rho, msq = cq / rho;
      double ss = rho * (msq - mean * mean);
      double delta = (1.0 - ss) / rho;
      double dl = delta > 0.0 ? delta : 0.0;
      double tau = mean - sqrt(dl);
      if (tau <= x) lc++;
    }
    tcnt[t] = lc;
  }
  __syncthreads();
  if (t == 0) {
    int r = 0;
    for (int i = 0; i < 256; i++) { int c = tcnt[i]; tcnt[i] = r; r += c; }
    sh_S = r;
  }
  __syncthreads();
  {
    int jstar = sh_S - 1;
    if (jstar >= base && jstar < base + 16) {
      double cs = tsum[t], cq = tsq[t], tau = 0.0;
      for (int ii = 0; ii <= jstar - base; ii++) {
        double x = 0.5 * (double)o2f((unsigned)(keys[base + ii] >> 32));
        cs += x; cq += x * x;
        double rho = (double)(base + ii + 1);
        double mean = cs / rho, msq = cq / rho;
        double ss = rho * (msq - mean * mean);
        double delta = (1.0 - ss) / rho;
        double dl = delta > 0.0 ? delta : 0.0;
        tau = mean - sqrt(dl);
      }
      sh_tau = tau;
    }
  }
  __syncthreads();
  const double tau = sh_tau;
  float ps[16], pa[16];
  {
    int lf = 0;
    for (int ii = 0; ii < 16; ii++) {
      int p = base + ii;
      ps[ii] = srow0[p] + srow1[p]; pa[ii] = arow[p];
      double d = 0.5 * (double)ps[ii] - tau;
      if (pa[ii] != 0.f && d > 0.0) lf++;
    }
    tcnt[t] = lf;
  }
  __syncthreads();
  if (t == 0) {
    int r = 0;
    for (int i = 0; i < 256; i++) { int c = tcnt[i]; tcnt[i] = r; r += c; }
    sh_m = r;
  }
  __syncthreads();
  const int m = sh_m;
  const int k0_ = sh_k[0], k1_ = sh_k[1], k2_ = sh_k[2], k3_ = sh_k[3], k4_ = sh_k[4];
  {
    int cex = tcnt[t];
    for (int ii = 0; ii < 16; ii++) {
      int p = base + ii;
      double d = 0.5 * (double)ps[ii] - tau;
      bool av = (pa[ii] != 0.f);
      bool sup = av && (d > 0.0);
      out[b * N + p] = sup ? (float)(d * d) : 0.0f;
      if (!sup) {
        int rank = m + p - cex;
        out[1 * BTc + b * N + p] = (av && rank < k0_) ? 1.f : 0.f;
        out[2 * BTc + b * N + p] = (av && rank < k1_) ? 1.f : 0.f;
        out[3 * BTc + b * N + p] = (av && rank < k2_) ? 1.f : 0.f;
        out[4 * BTc + b * N + p] = (av && rank < k3_) ? 1.f : 0.f;
        out[5 * BTc + b * N + p] = (av && rank < k4_) ? 1.f : 0.f;
      } else {
        cex++;
      }
    }
  }
  for (int r = t; r < m; r += 256) {
    int i = (int)(0xFFFFFFFFu - (unsigned)(keys[r] & 0xFFFFFFFFull));
    out[1 * BTc + b * N + i] = (r < k0_) ? 1.f : 0.f;
    out[2 * BTc + b * N + i] = (r < k1_) ? 1.f : 0.f;
    out[3 * BTc + b * N + i] = (r < k2_) ? 1.f : 0.f;
    out[4 * BTc + b * N + i] = (r < k3_) ? 1.f : 0.f;
    out[5 * BTc + b * N + i] = (r < k4_) ? 1.f : 0.f;
  }
}

extern "C" void kernel_launch(void* const* d_in, const int* in_sizes, int n_in,
                              void* d_out, int out_size, void* d_ws, size_t ws_size,
                              hipStream_t stream) {
  (void)in_sizes; (void)n_in; (void)out_size; (void)ws_size;
  const float* emb  = (const float*)d_in[0];
  const float* attn = (const float*)d_in[1];
  const float* ln_g = (const float*)d_in[2];
  const float* ln_b = (const float*)d_in[3];
  const float* W1   = (const float*)d_in[4];
  const float* b1   = (const float*)d_in[5];
  const float* W2   = (const float*)d_in[6];
  const float* b2   = (const float*)d_in[7];
  float* out = (float*)d_out;
  float* wsf = (float*)d_ws;
  float* mu     = wsf;
  float* rstd   = wsf + BTc;
  float* spart  = wsf + 2 * BTc;             // [2][BTc]
  ushort* w1s   = (ushort*)(wsf + 4 * BTc);  // 3 planes * 1.5 MB

  w1_split_k<<<384, 256, 0, stream>>>(W1, w1s);
  ln_stats_k<<<BTc / 4, 256, 0, stream>>>(emb, attn, mu, rstd);
  gemm_scores_mfma4<<<dim3(BTc / 64, 2), 512, 0, stream>>>(
      emb, attn, ln_g, ln_b, w1s, b1, W2, b2, mu, rstd, spart);
  entmax_rank_k<<<Bc, 256, 0, stream>>>(spart, spart + BTc, attn, out);
}